// Round 12
// baseline (244.785 us; speedup 1.0000x reference)
//
#include <hip/hip_runtime.h>
#include <hip/hip_bf16.h>

// Problem constants
// B=4, N=1024, M=4096, DQ=DC=1024, H=16, DH=64, INNER=1024, SCALE=0.125

typedef __attribute__((ext_vector_type(8))) short short8;          // 8 bf16 (MFMA A/B frag)
typedef __attribute__((ext_vector_type(8))) unsigned short u16x8;
typedef __attribute__((ext_vector_type(4))) float f32x4;
typedef __attribute__((ext_vector_type(16))) float f32x16;

static __device__ __forceinline__ void gload_lds16(const void* g, void* l) {
  __builtin_amdgcn_global_load_lds((const __attribute__((address_space(1))) void*)g,
                                   (__attribute__((address_space(3))) void*)l, 16, 0, 0);
}

static __device__ __forceinline__ unsigned short f2bf(float f) {
  __hip_bfloat16 h = __float2bfloat16(f);
  unsigned short u;
  __builtin_memcpy(&u, &h, 2);
  return u;
}

static __device__ __forceinline__ float bf2f(unsigned short u) {
  unsigned int x = (unsigned int)u << 16;
  float f;
  __builtin_memcpy(&f, &x, 4);
  return f;
}

// pack two positive floats to one u32 of 2 bf16 (round-half-up): 3 VALU ops.
static __device__ __forceinline__ unsigned int pack_rnd(float a, float b) {
  unsigned int ua, ub;
  __builtin_memcpy(&ua, &a, 4);
  __builtin_memcpy(&ub, &b, 4);
  return __builtin_amdgcn_perm(ua + 0x8000u, ub + 0x8000u, 0x03020706u);
}

// ---------------- cast fp32 -> bf16, 8 elems/thread ----------------
__global__ __launch_bounds__(256) void cast_bf16_kernel(const float* __restrict__ in,
                                                        unsigned short* __restrict__ out,
                                                        int n8) {
  int idx = blockIdx.x * 256 + threadIdx.x;
  int stride = gridDim.x * 256;
  for (int i = idx; i < n8; i += stride) {
    const float4* p = (const float4*)in + (size_t)i * 2;
    float4 a = p[0], b = p[1];
    u16x8 r;
    r[0] = f2bf(a.x); r[1] = f2bf(a.y); r[2] = f2bf(a.z); r[3] = f2bf(a.w);
    r[4] = f2bf(b.x); r[5] = f2bf(b.y); r[6] = f2bf(b.z); r[7] = f2bf(b.w);
    *((u16x8*)out + i) = r;
  }
}

// ---------------- mask -> fp32 additive bias (0 / -1e30) ----------------
__global__ __launch_bounds__(256) void mask_bias_kernel(const int* __restrict__ mask,
                                                        float* __restrict__ bias, int n) {
  int i = blockIdx.x * 256 + threadIdx.x;
  if (i < n) bias[i] = mask[i] ? 0.0f : -1e30f;
}

// ---------------- transpose + cast: W[K][N] fp32 -> Wt[N][K] bf16 ----------------
__global__ __launch_bounds__(256) void transpose_cast_kernel(const float* __restrict__ W,
                                                             unsigned short* __restrict__ Wt,
                                                             int K, int N) {
  __shared__ float tile[32][33];
  int n0 = blockIdx.x * 32, k0 = blockIdx.y * 32;
  int tx = threadIdx.x & 31, ty = threadIdx.x >> 5;
#pragma unroll
  for (int r = 0; r < 32; r += 8)
    tile[ty + r][tx] = W[(size_t)(k0 + ty + r) * N + n0 + tx];
  __syncthreads();
#pragma unroll
  for (int r = 0; r < 32; r += 8)
    Wt[(size_t)(n0 + ty + r) * K + k0 + tx] = f2bf(tile[tx][ty + r]);
}

// ---------------- 128^2 GEMM (m97 structure) for Q-proj and O-proj ----------------
// EPI 0: write Q layout [bh][n][64] bf16, PRESCALED by 0.125*log2(e)
// EPI 2: write fp32 outF[row*1024+col] = acc + bias[col]
template <int EPI>
__global__ __launch_bounds__(256, 2) void gemm_bt_kernel(
    const unsigned short* __restrict__ A, const unsigned short* __restrict__ Bt,
    int M, int N, int K,
    unsigned short* __restrict__ out0,
    float* __restrict__ outF, const float* __restrict__ bias) {
  __shared__ unsigned short As[128 * 64];
  __shared__ unsigned short Bs[128 * 64];
  const int tid = threadIdx.x;
  const int l = tid & 63;
  const int lq = l & 15, g = l >> 4;
  const int w = tid >> 6;
  const int wr = w >> 1, wc = w & 1;
  // XCD-chunked swizzle (nwg % 8 == 0 for all our grids)
  const int nwg = gridDim.x * gridDim.y;
  const int idl = blockIdx.y * gridDim.x + blockIdx.x;
  const int lin = (idl & 7) * (nwg >> 3) + (idl >> 3);
  const int m0 = (lin / gridDim.x) * 128, n0 = (lin % gridDim.x) * 128;

  f32x4 acc[4][4] = {};

  for (int k0 = 0; k0 < K; k0 += 64) {
    __syncthreads();
#pragma unroll
    for (int t = 0; t < 4; ++t) {
      int c = t * 256 + tid;
      int row = c >> 3, cb = c & 7;
      int srcoff = (cb * 16) ^ ((row & 7) << 4);
      char* la = (char*)As + t * 4096 + (tid & 192) * 16;  // wave-uniform base
      gload_lds16((const char*)(A + (size_t)(m0 + row) * K + k0) + srcoff, la);
      char* lb = (char*)Bs + t * 4096 + (tid & 192) * 16;
      gload_lds16((const char*)(Bt + (size_t)(n0 + row) * K + k0) + srcoff, lb);
    }
    __syncthreads();
#pragma unroll
    for (int ks = 0; ks < 2; ++ks) {
      short8 af[4], bfr[4];
#pragma unroll
      for (int mt = 0; mt < 4; ++mt) {
        int row = wr * 64 + mt * 16 + lq;
        af[mt] = *(const short8*)&As[row * 64 + ((ks * 32 + g * 8) ^ ((row & 7) << 3))];
      }
#pragma unroll
      for (int nt = 0; nt < 4; ++nt) {
        int row = wc * 64 + nt * 16 + lq;
        bfr[nt] = *(const short8*)&Bs[row * 64 + ((ks * 32 + g * 8) ^ ((row & 7) << 3))];
      }
#pragma unroll
      for (int mt = 0; mt < 4; ++mt)
#pragma unroll
        for (int nt = 0; nt < 4; ++nt)
          acc[mt][nt] =
              __builtin_amdgcn_mfma_f32_16x16x32_bf16(af[mt], bfr[nt], acc[mt][nt], 0, 0, 0);
    }
  }

#pragma unroll
  for (int mt = 0; mt < 4; ++mt) {
#pragma unroll
    for (int nt = 0; nt < 4; ++nt) {
#pragma unroll
      for (int r = 0; r < 4; ++r) {
        int row = m0 + wr * 64 + mt * 16 + g * 4 + r;
        int col = n0 + wc * 64 + nt * 16 + lq;
        float v = acc[mt][nt][r];
        if (EPI == 0) {
          int b = row >> 10, nq = row & 1023;
          int h = col >> 6, d = col & 63;
          // fold softmax scale (0.125 * log2 e) into Q
          out0[(((size_t)(b * 16 + h)) * 1024 + nq) * 64 + d] =
              f2bf(v * 0.18033688011112042f);
        } else {
          outF[(size_t)row * 1024 + col] = v + bias[col];
        }
      }
    }
  }
}

// ---------------- 256^2 deep-pipelined KV GEMM (counted vmcnt, 4-deep ring) ----------------
// C[16384, 2048] = cb * WkvT^T. BK=32, 32 K-steps. LDS ring: 4 bufs x (A 256x32
// + B 256x32) = 128 KB -> 1 block/CU (8 waves, 2/SIMD, like m201). Per step:
//   s_waitcnt vmcnt(8)   // step-t staging (issued 3 steps ago) retired, per wave
//   s_barrier            // all waves: buf[t&3] fully written; prior reads done
//   STAGE(t+3)           // 4 gload_lds -> buf[(t+3)&3] (= buf last read at t-1)
//   12 ds_read_b128 + 32 MFMA from buf[t&3]
// Raw s_barrier (no compiler vmcnt(0) drain) — loads stay in flight across
// barriers (T3+T4). Overwrite safety: a wave's ds_reads retire before its MFMAs
// issue (lgkm dep), which precede the barrier the stager passed.
// LDS chunk-XOR layout (chunk ^ (row&3)) keeps ds_read_b128 conflict-free and
// staging sources coalesced (64B permuted segments).
// EPI: cols<1024 -> K2[bh][d>>3][m][d&7]; cols>=1024 -> V2[bh][m>>3][d][m&7]
__global__ __launch_bounds__(512, 2) void gemm256_kv_kernel(
    const unsigned short* __restrict__ A, const unsigned short* __restrict__ Bt,
    unsigned short* __restrict__ K2out, unsigned short* __restrict__ V2out) {
  __shared__ unsigned short lds[4 * 16384];  // 128 KB
  const int tid = threadIdx.x;
  const int l = tid & 63;
  const int lq = l & 15, g = l >> 4;
  const int w = tid >> 6;           // 0..7
  const int wr = w >> 2, wc = w & 3;
  // XCD-chunked swizzle (nwg = 512, %8 == 0)
  const int nwg = gridDim.x * gridDim.y;
  const int idl = blockIdx.y * gridDim.x + blockIdx.x;
  const int lin = (idl & 7) * (nwg >> 3) + (idl >> 3);
  const int m0 = (lin / gridDim.x) * 256;
  const int n0 = (lin % gridDim.x) * 256;

  // staging sources: thread c in [0,1024) covers (row = c>>2, chunk = c&3);
  // global column chunk pre-swizzled: chunk ^ (row&3)
  const int rA0 = tid >> 2, rA1 = (512 + tid) >> 2;
  const int ch = tid & 3;
  const unsigned short* sA0 = A + (size_t)(m0 + rA0) * 1024 + ((ch ^ (rA0 & 3)) << 3);
  const unsigned short* sA1 = A + (size_t)(m0 + rA1) * 1024 + ((ch ^ (rA1 & 3)) << 3);
  const unsigned short* sB0 = Bt + (size_t)(n0 + rA0) * 1024 + ((ch ^ (rA0 & 3)) << 3);
  const unsigned short* sB1 = Bt + (size_t)(n0 + rA1) * 1024 + ((ch ^ (rA1 & 3)) << 3);
  const int wub = (tid & 448) * 16;  // wave-uniform LDS dest base (lane x16 added by HW)

  // frag read offsets (loop-invariant; chunk XOR depends only on lq&3)
  const int coff = (g ^ (lq & 3)) << 4;
  const int aoff = (wr * 128 + lq) * 64 + coff;
  const int boff = 16384 + (wc * 64 + lq) * 64 + coff;

  f32x4 acc[8][4] = {};

#define STAGE256(t_, s_)                                                   \
  do {                                                                     \
    char* _b = (char*)lds + (s_) * 32768;                                  \
    gload_lds16(sA0 + (t_) * 32, _b + wub);                                \
    gload_lds16(sA1 + (t_) * 32, _b + 8192 + wub);                         \
    gload_lds16(sB0 + (t_) * 32, _b + 16384 + wub);                        \
    gload_lds16(sB1 + (t_) * 32, _b + 24576 + wub);                        \
  } while (0)

#define COMPUTE256(s_)                                                     \
  do {                                                                     \
    const char* _pa = (const char*)lds + (s_) * 32768 + aoff;              \
    const char* _pb = (const char*)lds + (s_) * 32768 + boff;              \
    short8 af[8], bfv[4];                                                  \
    _Pragma("unroll") for (int mt = 0; mt < 8; ++mt)                       \
        af[mt] = *(const short8*)(_pa + mt * 1024);                        \
    _Pragma("unroll") for (int nt = 0; nt < 4; ++nt)                       \
        bfv[nt] = *(const short8*)(_pb + nt * 1024);                       \
    __builtin_amdgcn_s_setprio(1);                                         \
    _Pragma("unroll") for (int mt = 0; mt < 8; ++mt)                       \
        _Pragma("unroll") for (int nt = 0; nt < 4; ++nt)                   \
            acc[mt][nt] = __builtin_amdgcn_mfma_f32_16x16x32_bf16(         \
                af[mt], bfv[nt], acc[mt][nt], 0, 0, 0);                    \
    __builtin_amdgcn_s_setprio(0);                                         \
  } while (0)

#define PHASE256(vm_, dostage_, t_, s_stage_, s_comp_)                     \
  do {                                                                     \
    asm volatile("s_waitcnt vmcnt(" #vm_ ")" ::: "memory");                \
    __builtin_amdgcn_s_barrier();                                          \
    __builtin_amdgcn_sched_barrier(0);                                     \
    if (dostage_) STAGE256(t_, s_stage_);                                  \
    COMPUTE256(s_comp_);                                                   \
  } while (0)

  // prologue: 3-deep prefetch
  STAGE256(0, 0);
  STAGE256(1, 1);
  STAGE256(2, 2);

  for (int it = 0; it < 7; ++it) {  // steps t = 0..27
    const int t0 = it * 4;
    PHASE256(8, true, t0 + 3, 3, 0);
    PHASE256(8, true, t0 + 4, 0, 1);
    PHASE256(8, true, t0 + 5, 1, 2);
    PHASE256(8, true, t0 + 6, 2, 3);
  }
  PHASE256(8, true, 31, 3, 0);   // t=28 (stages last step)
  PHASE256(8, false, 0, 0, 1);   // t=29
  PHASE256(4, false, 0, 0, 2);   // t=30
  PHASE256(0, false, 0, 0, 3);   // t=31

#undef PHASE256
#undef COMPUTE256
#undef STAGE256

  // epilogue: K2/V2 scatter (per-tile uniform K-vs-V since n0 is a multiple of 256)
#pragma unroll
  for (int mt = 0; mt < 8; ++mt) {
#pragma unroll
    for (int nt = 0; nt < 4; ++nt) {
      int col = n0 + wc * 64 + nt * 16 + lq;
      int rowb = m0 + wr * 128 + mt * 16 + g * 4;
      int b = rowb >> 12, mm = rowb & 4095;
      if (col < 1024) {
        int h = col >> 6, d = col & 63;
#pragma unroll
        for (int r = 0; r < 4; ++r) {
          size_t off =
              (((size_t)(b * 16 + h) * 8 + (d >> 3)) * 4096 + (mm + r)) * 8 + (d & 7);
          K2out[off] = f2bf(acc[mt][nt][r]);
        }
      } else {
        int hv = col - 1024;
        int h = hv >> 6, d = hv & 63;
        ushort4 pk;
        pk.x = f2bf(acc[mt][nt][0]);
        pk.y = f2bf(acc[mt][nt][1]);
        pk.z = f2bf(acc[mt][nt][2]);
        pk.w = f2bf(acc[mt][nt][3]);
        size_t off = (((size_t)(b * 16 + h) * 512 + (mm >> 3)) * 64 + d) * 8 + (mm & 7);
        *(ushort4*)&V2out[off] = pk;
      }
    }
  }
}

// ---------------- fused attention (j-split, in-register P, double-buffered) ----------------
// Round-11 verified: conflict-free d-block-major LDS, sigma-permuted K,
// in-register P, zero-shuffle PV, mask as MFMA C-seed, Q prescaled, KVBLK=64
// double-buffered staging (STAGE(t+1) before compute(t), one barrier/tile).
__global__ __launch_bounds__(256, 3) void attn_kernel(
    const unsigned short* __restrict__ K2, const unsigned short* __restrict__ V2,
    const unsigned short* __restrict__ Q, const float* __restrict__ maskb,
    unsigned short* __restrict__ numP, float* __restrict__ denP) {
  __shared__ unsigned short Ks[2][8 * 64 * 8];  // [buf][db][jj (sigma'd)][8 d-elems]
  __shared__ unsigned short Vt[2][8 * 64 * 8];  // [buf][jb][d][8 j-elems]

  const int tid = threadIdx.x;
  const int l = tid & 63, w = tid >> 6;
  const int lq = l & 31;  // q within the wave's 32-row block / row index
  const int hi = l >> 5;  // lane half

  // XCD-affine decode: id&7 = XCD; 8 consecutive same-XCD blocks share (bh,js)
  const int id = blockIdx.x;
  const int xcd = id & 7;
  const int kk = id >> 3;
  const int qi = kk & 7;
  const int pr = xcd * 32 + (kk >> 3);
  const int bh = pr & 63, js = pr >> 6;
  const int b = bh >> 4;
  const int q0 = qi * 128 + w * 32;

  const unsigned short* Qh = Q + (size_t)bh * 1024 * 64;
  const unsigned short* Kh = K2 + (size_t)bh * 8 * 4096 * 8;   // [db][m][8]
  const unsigned short* Vh = V2 + (size_t)bh * 512 * 64 * 8;   // [jb][d][8]
  const float* bb = maskb + b * 4096;

  const float CLIP2 = 7.213475204444817f;  // 5 * log2(e)

  // Q fragments (B-operand): lane holds Q[q0+lq][kc*16 + hi*8 + e], prescaled
  short8 qf[4];
#pragma unroll
  for (int kc = 0; kc < 4; ++kc)
    qf[kc] = *(const short8*)&Qh[(size_t)(q0 + lq) * 64 + kc * 16 + hi * 8];

  f32x16 oacc[2] = {};
  float den = 0.f;

  const int jbeg = js * 16, jend = jbeg + 16;  // 16 tiles of 64 j

#define STAGE_KV(bi_, j0_)                                                       \
  do {                                                                           \
    _Pragma("unroll") for (int t = 0; t < 2; ++t) {                              \
      int c = t * 256 + tid;                                                     \
      int db = c >> 6, jj = c & 63;                                              \
      int sig = (jj & 0x33) | ((jj & 4) << 1) | ((jj & 8) >> 1);                 \
      char* lk = (char*)(&Ks[bi_][0]) + t * 4096 + (tid & 192) * 16;             \
      gload_lds16((const char*)(Kh + ((size_t)db * 4096 + (j0_) + sig) * 8), lk);\
      char* lv = (char*)(&Vt[bi_][0]) + t * 4096 + (tid & 192) * 16;             \
      gload_lds16((const char*)(Vh + ((size_t)(((j0_) >> 3) + db) * 64 + jj) * 8), lv); \
    }                                                                            \
  } while (0)

  // prologue: stage first tile into buf 0
  STAGE_KV(0, jbeg * 64);
  __syncthreads();

  for (int jt = jbeg; jt < jend; ++jt) {
    const int j0 = jt * 64;
    const int cur = jt & 1;  // jbeg is even (js*16)
    // issue next tile's staging into the other buffer; lands during compute
    if (jt + 1 < jend) STAGE_KV(cur ^ 1, j0 + 64);

    const unsigned short* Kc = &Ks[cur][0];
    const unsigned short* Vc = &Vt[cur][0];

#pragma unroll
    for (int half = 0; half < 2; ++half) {
      // seed S accumulator with mask bias at sigma-mapped reg position:
      // reg r (bq=r>>2) -> j = (r&3) + 4*(bq&1) + 8*hi + 16*(bq>>1)
      f32x16 sacc;
#pragma unroll
      for (int bq = 0; bq < 4; ++bq) {
        f32x4 m4 = *(const f32x4*)&bb[j0 + half * 32 + ((bq & 1) << 2) + (hi << 3) +
                                      ((bq >> 1) << 4)];
        sacc[bq * 4 + 0] = m4[0];
        sacc[bq * 4 + 1] = m4[1];
        sacc[bq * 4 + 2] = m4[2];
        sacc[bq * 4 + 3] = m4[3];
      }
      // S^T = K * Q^T : A-frag = 32 lanes x consecutive 16B (conflict-free)
      __builtin_amdgcn_s_setprio(1);
#pragma unroll
      for (int kc = 0; kc < 4; ++kc) {
        short8 kf = *(const short8*)((const char*)Kc + (2 * kc + hi) * 1024 +
                                     (half * 32 + lq) * 16);
        sacc = __builtin_amdgcn_mfma_f32_32x32x16_bf16(kf, qf[kc], sacc, 0, 0, 0);
      }
      __builtin_amdgcn_s_setprio(0);
      // softmax: clamp via med3 then exp2; masked rows hit -CLIP2 exactly
#pragma unroll
      for (int r = 0; r < 16; ++r) {
        float v = __builtin_amdgcn_fmed3f(sacc[r], -CLIP2, CLIP2);
        float p = __builtin_amdgcn_exp2f(v);
        sacc[r] = p;
        den += p;
      }
      // pack pairs (reg 2i, 2i+1): wds[i] holds P for A-frag word i directly
      unsigned int wds[8];
#pragma unroll
      for (int i = 0; i < 8; ++i) wds[i] = pack_rnd(sacc[i * 2], sacc[i * 2 + 1]);
      // PV: A-frag for kt = wds[4kt..4kt+3]; V B-frag conflict-free
      __builtin_amdgcn_s_setprio(1);
#pragma unroll
      for (int kt = 0; kt < 2; ++kt) {
        union { unsigned int u[4]; short8 s; } pa;
        pa.u[0] = wds[kt * 4 + 0];
        pa.u[1] = wds[kt * 4 + 1];
        pa.u[2] = wds[kt * 4 + 2];
        pa.u[3] = wds[kt * 4 + 3];
#pragma unroll
        for (int dt = 0; dt < 2; ++dt) {
          short8 vf = *(const short8*)((const char*)Vc +
              (4 * half + 2 * kt + hi) * 1024 + (dt * 32 + lq) * 16);
          oacc[dt] = __builtin_amdgcn_mfma_f32_32x32x16_bf16(pa.s, vf, oacc[dt], 0, 0, 0);
        }
      }
      __builtin_amdgcn_s_setprio(0);
    }
    // barrier: drains (already-landed) next-tile staging; protects buf reuse
    __syncthreads();
  }
#undef STAGE_KV

  // denominator: lanes l and l^32 hold disjoint j-sums for the same q
  den += __shfl_xor(den, 32);
  if (l < 32) denP[(((size_t)js * 64 + bh) * 1024) + q0 + l] = den;

  // numerator partials: q from reg index (PV C-layout), d from lane
#pragma unroll
  for (int dt = 0; dt < 2; ++dt)
#pragma unroll
    for (int r = 0; r < 16; ++r) {
      int q = q0 + (r & 3) + 8 * (r >> 2) + 4 * hi;
      int d = dt * 32 + lq;
      numP[((((size_t)js * 64 + bh) * 1024 + q) * 64) + d] = f2bf(oacc[dt][r]);
    }
}

// ---------------- combine j-split partials, divide, write Ob ----------------
__global__ __launch_bounds__(256) void attn_reduce_kernel(
    const unsigned short* __restrict__ numP, const float* __restrict__ denP,
    unsigned short* __restrict__ Ob) {
  int id = blockIdx.x * 256 + threadIdx.x;  // 0 .. 524287
  int d8 = id & 7;
  int q = (id >> 3) & 1023;
  int bh = id >> 13;
  int b = bh >> 4, h = bh & 15;
  float den = 0.f;
  float o[8] = {0.f, 0.f, 0.f, 0.f, 0.f, 0.f, 0.f, 0.f};
#pragma unroll
  for (int s = 0; s < 4; ++s) {
    const unsigned short* np =
        numP + ((((size_t)s * 64 + bh) * 1024 + q) * 64 + d8 * 8);
    u16x8 v = *(const u16x8*)np;
    den += denP[((size_t)s * 64 + bh) * 1024 + q];
#pragma unroll
    for (int e = 0; e < 8; ++e) o[e] += bf2f(v[e]);
  }
  float r = 1.0f / den;
  u16x8 outv;
#pragma unroll
  for (int e = 0; e < 8; ++e) outv[e] = f2bf(o[e] * r);
  *(u16x8*)&Ob[(((size_t)b * 1024 + q) * 1024) + h * 64 + d8 * 8] = outv;
}

// ---------------- launcher ----------------
extern "C" void kernel_launch(void* const* d_in, const int* in_sizes, int n_in,
                              void* d_out, int out_size, void* d_ws, size_t ws_size,
                              hipStream_t stream) {
  (void)in_sizes; (void)n_in; (void)out_size; (void)ws_size;
  const float* x    = (const float*)d_in[0];
  const float* ctx  = (const float*)d_in[1];
  const int*   mask = (const int*)d_in[2];
  const float* Wq   = (const float*)d_in[3];
  const float* Wkv  = (const float*)d_in[4];
  const float* Wo   = (const float*)d_in[5];
  const float* bo   = (const float*)d_in[6];
  float* out = (float*)d_out;

  char* ws = (char*)d_ws;
  const size_t MB = 1 << 20;
  // 0..40 MiB region is time-shared: {xb, cb} before attention; {numP, denP,
  // maskbias} after cb is consumed by the KV-GEMM (stream-ordered).
  unsigned short* numP = (unsigned short*)(ws + 0);        // 32 MiB : [4][64][1024][64] bf16
  float*          denP = (float*)(ws + 32 * MB);           // 1 MiB  : [4][64][1024] fp32
  float*          mbias= (float*)(ws + 33 * MB);           // 64 KiB : [4][4096] fp32
  unsigned short* xb   = (unsigned short*)(ws + 0);        // 8 MiB  : x bf16 [4096][1024]
  unsigned short* cb   = (unsigned short*)(ws + 8 * MB);   // 32 MiB : ctx bf16 [16384][1024]
  unsigned short* WqT  = (unsigned short*)(ws + 40 * MB);  // 2 MiB
  unsigned short* WkvT = (unsigned short*)(ws + 42 * MB);  // 4 MiB
  unsigned short* WoT  = (unsigned short*)(ws + 46 * MB);  // 2 MiB
  unsigned short* Qb   = (unsigned short*)(ws + 48 * MB);  // 8 MiB  : [bh][1024][64] (prescaled)
  unsigned short* K2   = (unsigned short*)(ws + 56 * MB);  // 32 MiB : [bh][d/8][4096][8]
  unsigned short* V2   = (unsigned short*)(ws + 88 * MB);  // 32 MiB : [bh][m/8][64][8]
  unsigned short* Ob   = (unsigned short*)(ws + 120 * MB); // 8 MiB  : [b][n][1024]

  cast_bf16_kernel<<<2048, 256, 0, stream>>>(x, xb, (4 * 1024 * 1024) / 8);
  cast_bf16_kernel<<<2048, 256, 0, stream>>>(ctx, cb, (16 * 1024 * 1024) / 8);
  transpose_cast_kernel<<<dim3(32, 32), 256, 0, stream>>>(Wq, WqT, 1024, 1024);
  transpose_cast_kernel<<<dim3(64, 32), 256, 0, stream>>>(Wkv, WkvT, 1024, 2048);
  transpose_cast_kernel<<<dim3(32, 32), 256, 0, stream>>>(Wo, WoT, 1024, 1024);

  gemm_bt_kernel<0><<<dim3(8, 32), 256, 0, stream>>>(xb, WqT, 4096, 1024, 1024,
                                                     Qb, (float*)nullptr,
                                                     (const float*)nullptr);
  gemm256_kv_kernel<<<dim3(8, 64), 512, 0, stream>>>(cb, WkvT, K2, V2);
  // mbias overlaps the (now-dead) cb region; launched after the KV-GEMM reads cb
  mask_bias_kernel<<<64, 256, 0, stream>>>(mask, mbias, 4 * 4096);
  attn_kernel<<<2048, 256, 0, stream>>>(K2, V2, Qb, mbias, numP, denP);
  attn_reduce_kernel<<<2048, 256, 0, stream>>>(numP, denP, Ob);
  gemm_bt_kernel<2><<<dim3(8, 32), 256, 0, stream>>>(Ob, WoT, 4096, 1024, 1024,
                                                     (unsigned short*)nullptr,
                                                     out, bo);
}

// Round 13
// 240.246 us; speedup vs baseline: 1.0189x; 1.0189x over previous
//
#include <hip/hip_runtime.h>
#include <hip/hip_bf16.h>

// Problem constants
// B=4, N=1024, M=4096, DQ=DC=1024, H=16, DH=64, INNER=1024, SCALE=0.125

typedef __attribute__((ext_vector_type(8))) short short8;          // 8 bf16 (MFMA A/B frag)
typedef __attribute__((ext_vector_type(8))) unsigned short u16x8;
typedef __attribute__((ext_vector_type(4))) float f32x4;
typedef __attribute__((ext_vector_type(16))) float f32x16;

static __device__ __forceinline__ void gload_lds16(const void* g, void* l) {
  __builtin_amdgcn_global_load_lds((const __attribute__((address_space(1))) void*)g,
                                   (__attribute__((address_space(3))) void*)l, 16, 0, 0);
}

static __device__ __forceinline__ unsigned short f2bf(float f) {
  __hip_bfloat16 h = __float2bfloat16(f);
  unsigned short u;
  __builtin_memcpy(&u, &h, 2);
  return u;
}

static __device__ __forceinline__ float bf2f(unsigned short u) {
  unsigned int x = (unsigned int)u << 16;
  float f;
  __builtin_memcpy(&f, &x, 4);
  return f;
}

// pack two positive floats to one u32 of 2 bf16 (round-half-up): 3 VALU ops.
static __device__ __forceinline__ unsigned int pack_rnd(float a, float b) {
  unsigned int ua, ub;
  __builtin_memcpy(&ua, &a, 4);
  __builtin_memcpy(&ub, &b, 4);
  return __builtin_amdgcn_perm(ua + 0x8000u, ub + 0x8000u, 0x03020706u);
}

// pack two positive floats to one u32 of 2 bf16 (TRUNCATE): 1 VALU op.
// Used only for P in attention: P>0, den kept fp32-exact, bias <= 0.39% on
// the numerator only -> <= ~5e-4 absmax contribution (verified margin 2x+).
static __device__ __forceinline__ unsigned int pack_trunc(float a, float b) {
  unsigned int ua, ub;
  __builtin_memcpy(&ua, &a, 4);
  __builtin_memcpy(&ub, &b, 4);
  return __builtin_amdgcn_perm(ua, ub, 0x03020706u);
}

// ---------------- cast fp32 -> bf16, 8 elems/thread ----------------
__global__ __launch_bounds__(256) void cast_bf16_kernel(const float* __restrict__ in,
                                                        unsigned short* __restrict__ out,
                                                        int n8) {
  int idx = blockIdx.x * 256 + threadIdx.x;
  int stride = gridDim.x * 256;
  for (int i = idx; i < n8; i += stride) {
    const float4* p = (const float4*)in + (size_t)i * 2;
    float4 a = p[0], b = p[1];
    u16x8 r;
    r[0] = f2bf(a.x); r[1] = f2bf(a.y); r[2] = f2bf(a.z); r[3] = f2bf(a.w);
    r[4] = f2bf(b.x); r[5] = f2bf(b.y); r[6] = f2bf(b.z); r[7] = f2bf(b.w);
    *((u16x8*)out + i) = r;
  }
}

// ---------------- mask -> fp32 additive bias (0 / -1e30) ----------------
__global__ __launch_bounds__(256) void mask_bias_kernel(const int* __restrict__ mask,
                                                        float* __restrict__ bias, int n) {
  int i = blockIdx.x * 256 + threadIdx.x;
  if (i < n) bias[i] = mask[i] ? 0.0f : -1e30f;
}

// ---------------- transpose + cast: W[K][N] fp32 -> Wt[N][K] bf16 ----------------
__global__ __launch_bounds__(256) void transpose_cast_kernel(const float* __restrict__ W,
                                                             unsigned short* __restrict__ Wt,
                                                             int K, int N) {
  __shared__ float tile[32][33];
  int n0 = blockIdx.x * 32, k0 = blockIdx.y * 32;
  int tx = threadIdx.x & 31, ty = threadIdx.x >> 5;
#pragma unroll
  for (int r = 0; r < 32; r += 8)
    tile[ty + r][tx] = W[(size_t)(k0 + ty + r) * N + n0 + tx];
  __syncthreads();
#pragma unroll
  for (int r = 0; r < 32; r += 8)
    Wt[(size_t)(n0 + ty + r) * K + k0 + tx] = f2bf(tile[tx][ty + r]);
}

// ---------------- 128^2 GEMM (m97 structure) for Q-proj and O-proj ----------------
// EPI 0: write Q layout [bh][n][64] bf16, PRESCALED by 0.125*log2(e)
// EPI 2: write fp32 outF[row*1024+col] = acc + bias[col]
template <int EPI>
__global__ __launch_bounds__(256, 2) void gemm_bt_kernel(
    const unsigned short* __restrict__ A, const unsigned short* __restrict__ Bt,
    int M, int N, int K,
    unsigned short* __restrict__ out0,
    float* __restrict__ outF, const float* __restrict__ bias) {
  __shared__ unsigned short As[128 * 64];
  __shared__ unsigned short Bs[128 * 64];
  const int tid = threadIdx.x;
  const int l = tid & 63;
  const int lq = l & 15, g = l >> 4;
  const int w = tid >> 6;
  const int wr = w >> 1, wc = w & 1;
  // XCD-chunked swizzle (nwg % 8 == 0 for all our grids)
  const int nwg = gridDim.x * gridDim.y;
  const int idl = blockIdx.y * gridDim.x + blockIdx.x;
  const int lin = (idl & 7) * (nwg >> 3) + (idl >> 3);
  const int m0 = (lin / gridDim.x) * 128, n0 = (lin % gridDim.x) * 128;

  f32x4 acc[4][4] = {};

  for (int k0 = 0; k0 < K; k0 += 64) {
    __syncthreads();
#pragma unroll
    for (int t = 0; t < 4; ++t) {
      int c = t * 256 + tid;
      int row = c >> 3, cb = c & 7;
      int srcoff = (cb * 16) ^ ((row & 7) << 4);
      char* la = (char*)As + t * 4096 + (tid & 192) * 16;  // wave-uniform base
      gload_lds16((const char*)(A + (size_t)(m0 + row) * K + k0) + srcoff, la);
      char* lb = (char*)Bs + t * 4096 + (tid & 192) * 16;
      gload_lds16((const char*)(Bt + (size_t)(n0 + row) * K + k0) + srcoff, lb);
    }
    __syncthreads();
#pragma unroll
    for (int ks = 0; ks < 2; ++ks) {
      short8 af[4], bfr[4];
#pragma unroll
      for (int mt = 0; mt < 4; ++mt) {
        int row = wr * 64 + mt * 16 + lq;
        af[mt] = *(const short8*)&As[row * 64 + ((ks * 32 + g * 8) ^ ((row & 7) << 3))];
      }
#pragma unroll
      for (int nt = 0; nt < 4; ++nt) {
        int row = wc * 64 + nt * 16 + lq;
        bfr[nt] = *(const short8*)&Bs[row * 64 + ((ks * 32 + g * 8) ^ ((row & 7) << 3))];
      }
#pragma unroll
      for (int mt = 0; mt < 4; ++mt)
#pragma unroll
        for (int nt = 0; nt < 4; ++nt)
          acc[mt][nt] =
              __builtin_amdgcn_mfma_f32_16x16x32_bf16(af[mt], bfr[nt], acc[mt][nt], 0, 0, 0);
    }
  }

#pragma unroll
  for (int mt = 0; mt < 4; ++mt) {
#pragma unroll
    for (int nt = 0; nt < 4; ++nt) {
#pragma unroll
      for (int r = 0; r < 4; ++r) {
        int row = m0 + wr * 64 + mt * 16 + g * 4 + r;
        int col = n0 + wc * 64 + nt * 16 + lq;
        float v = acc[mt][nt][r];
        if (EPI == 0) {
          int b = row >> 10, nq = row & 1023;
          int h = col >> 6, d = col & 63;
          // fold softmax scale (0.125 * log2 e) into Q
          out0[(((size_t)(b * 16 + h)) * 1024 + nq) * 64 + d] =
              f2bf(v * 0.18033688011112042f);
        } else {
          outF[(size_t)row * 1024 + col] = v + bias[col];
        }
      }
    }
  }
}

// ---------------- 256^2 deep-pipelined KV GEMM (counted vmcnt, 4-deep ring) ----------------
// (round-12 verified; equal perf to the 128^2 structure — kept.)
// EPI: cols<1024 -> K2[bh][d>>3][m][d&7]; cols>=1024 -> V2[bh][m>>3][d][m&7]
__global__ __launch_bounds__(512, 2) void gemm256_kv_kernel(
    const unsigned short* __restrict__ A, const unsigned short* __restrict__ Bt,
    unsigned short* __restrict__ K2out, unsigned short* __restrict__ V2out) {
  __shared__ unsigned short lds[4 * 16384];  // 128 KB
  const int tid = threadIdx.x;
  const int l = tid & 63;
  const int lq = l & 15, g = l >> 4;
  const int w = tid >> 6;           // 0..7
  const int wr = w >> 2, wc = w & 3;
  // XCD-chunked swizzle (nwg = 512, %8 == 0)
  const int nwg = gridDim.x * gridDim.y;
  const int idl = blockIdx.y * gridDim.x + blockIdx.x;
  const int lin = (idl & 7) * (nwg >> 3) + (idl >> 3);
  const int m0 = (lin / gridDim.x) * 256;
  const int n0 = (lin % gridDim.x) * 256;

  const int rA0 = tid >> 2, rA1 = (512 + tid) >> 2;
  const int ch = tid & 3;
  const unsigned short* sA0 = A + (size_t)(m0 + rA0) * 1024 + ((ch ^ (rA0 & 3)) << 3);
  const unsigned short* sA1 = A + (size_t)(m0 + rA1) * 1024 + ((ch ^ (rA1 & 3)) << 3);
  const unsigned short* sB0 = Bt + (size_t)(n0 + rA0) * 1024 + ((ch ^ (rA0 & 3)) << 3);
  const unsigned short* sB1 = Bt + (size_t)(n0 + rA1) * 1024 + ((ch ^ (rA1 & 3)) << 3);
  const int wub = (tid & 448) * 16;  // wave-uniform LDS dest base

  const int coff = (g ^ (lq & 3)) << 4;
  const int aoff = (wr * 128 + lq) * 64 + coff;
  const int boff = 16384 + (wc * 64 + lq) * 64 + coff;

  f32x4 acc[8][4] = {};

#define STAGE256(t_, s_)                                                   \
  do {                                                                     \
    char* _b = (char*)lds + (s_) * 32768;                                  \
    gload_lds16(sA0 + (t_) * 32, _b + wub);                                \
    gload_lds16(sA1 + (t_) * 32, _b + 8192 + wub);                         \
    gload_lds16(sB0 + (t_) * 32, _b + 16384 + wub);                        \
    gload_lds16(sB1 + (t_) * 32, _b + 24576 + wub);                        \
  } while (0)

#define COMPUTE256(s_)                                                     \
  do {                                                                     \
    const char* _pa = (const char*)lds + (s_) * 32768 + aoff;              \
    const char* _pb = (const char*)lds + (s_) * 32768 + boff;              \
    short8 af[8], bfv[4];                                                  \
    _Pragma("unroll") for (int mt = 0; mt < 8; ++mt)                       \
        af[mt] = *(const short8*)(_pa + mt * 1024);                        \
    _Pragma("unroll") for (int nt = 0; nt < 4; ++nt)                       \
        bfv[nt] = *(const short8*)(_pb + nt * 1024);                       \
    __builtin_amdgcn_s_setprio(1);                                         \
    _Pragma("unroll") for (int mt = 0; mt < 8; ++mt)                       \
        _Pragma("unroll") for (int nt = 0; nt < 4; ++nt)                   \
            acc[mt][nt] = __builtin_amdgcn_mfma_f32_16x16x32_bf16(         \
                af[mt], bfv[nt], acc[mt][nt], 0, 0, 0);                    \
    __builtin_amdgcn_s_setprio(0);                                         \
  } while (0)

#define PHASE256(vm_, dostage_, t_, s_stage_, s_comp_)                     \
  do {                                                                     \
    asm volatile("s_waitcnt vmcnt(" #vm_ ")" ::: "memory");                \
    __builtin_amdgcn_s_barrier();                                          \
    __builtin_amdgcn_sched_barrier(0);                                     \
    if (dostage_) STAGE256(t_, s_stage_);                                  \
    COMPUTE256(s_comp_);                                                   \
  } while (0)

  STAGE256(0, 0);
  STAGE256(1, 1);
  STAGE256(2, 2);

  for (int it = 0; it < 7; ++it) {  // steps t = 0..27
    const int t0 = it * 4;
    PHASE256(8, true, t0 + 3, 3, 0);
    PHASE256(8, true, t0 + 4, 0, 1);
    PHASE256(8, true, t0 + 5, 1, 2);
    PHASE256(8, true, t0 + 6, 2, 3);
  }
  PHASE256(8, true, 31, 3, 0);   // t=28 (stages last step)
  PHASE256(8, false, 0, 0, 1);   // t=29
  PHASE256(4, false, 0, 0, 2);   // t=30
  PHASE256(0, false, 0, 0, 3);   // t=31

#undef PHASE256
#undef COMPUTE256
#undef STAGE256

#pragma unroll
  for (int mt = 0; mt < 8; ++mt) {
#pragma unroll
    for (int nt = 0; nt < 4; ++nt) {
      int col = n0 + wc * 64 + nt * 16 + lq;
      int rowb = m0 + wr * 128 + mt * 16 + g * 4;
      int b = rowb >> 12, mm = rowb & 4095;
      if (col < 1024) {
        int h = col >> 6, d = col & 63;
#pragma unroll
        for (int r = 0; r < 4; ++r) {
          size_t off =
              (((size_t)(b * 16 + h) * 8 + (d >> 3)) * 4096 + (mm + r)) * 8 + (d & 7);
          K2out[off] = f2bf(acc[mt][nt][r]);
        }
      } else {
        int hv = col - 1024;
        int h = hv >> 6, d = hv & 63;
        ushort4 pk;
        pk.x = f2bf(acc[mt][nt][0]);
        pk.y = f2bf(acc[mt][nt][1]);
        pk.z = f2bf(acc[mt][nt][2]);
        pk.w = f2bf(acc[mt][nt][3]);
        size_t off = (((size_t)(b * 16 + h) * 512 + (mm >> 3)) * 64 + d) * 8 + (mm & 7);
        *(ushort4*)&V2out[off] = pk;
      }
    }
  }
}

// ---------------- fused attention (two-phase halves, in-register P) ----------------
// Round-11 verified data path (conflict-free d-block-major LDS, sigma-permuted
// K, in-register P, zero-shuffle PV, mask as MFMA C-seed, Q prescaled, KVBLK=64
// dbuf). NEW (all reordering / VALU trims, mappings unchanged):
//  - two-phase: QK^T for BOTH halves first, then softmax+pack both, then PV
//    both -> half-1 MFMA overlaps half-0 softmax (breaks the serial chain).
//  - den in 4 accumulators (breaks 32-long serial add chain).
//  - P packed by single v_perm (truncate; den stays fp32-exact).
__global__ __launch_bounds__(256, 3) void attn_kernel(
    const unsigned short* __restrict__ K2, const unsigned short* __restrict__ V2,
    const unsigned short* __restrict__ Q, const float* __restrict__ maskb,
    unsigned short* __restrict__ numP, float* __restrict__ denP) {
  __shared__ unsigned short Ks[2][8 * 64 * 8];  // [buf][db][jj (sigma'd)][8 d-elems]
  __shared__ unsigned short Vt[2][8 * 64 * 8];  // [buf][jb][d][8 j-elems]

  const int tid = threadIdx.x;
  const int l = tid & 63, w = tid >> 6;
  const int lq = l & 31;  // q within the wave's 32-row block / row index
  const int hi = l >> 5;  // lane half

  // XCD-affine decode: id&7 = XCD; 8 consecutive same-XCD blocks share (bh,js)
  const int id = blockIdx.x;
  const int xcd = id & 7;
  const int kk = id >> 3;
  const int qi = kk & 7;
  const int pr = xcd * 32 + (kk >> 3);
  const int bh = pr & 63, js = pr >> 6;
  const int b = bh >> 4;
  const int q0 = qi * 128 + w * 32;

  const unsigned short* Qh = Q + (size_t)bh * 1024 * 64;
  const unsigned short* Kh = K2 + (size_t)bh * 8 * 4096 * 8;   // [db][m][8]
  const unsigned short* Vh = V2 + (size_t)bh * 512 * 64 * 8;   // [jb][d][8]
  const float* bb = maskb + b * 4096;

  const float CLIP2 = 7.213475204444817f;  // 5 * log2(e)

  // Q fragments (B-operand): lane holds Q[q0+lq][kc*16 + hi*8 + e], prescaled
  short8 qf[4];
#pragma unroll
  for (int kc = 0; kc < 4; ++kc)
    qf[kc] = *(const short8*)&Qh[(size_t)(q0 + lq) * 64 + kc * 16 + hi * 8];

  f32x16 oacc[2] = {};
  float den4[4] = {};

  const int jbeg = js * 16, jend = jbeg + 16;  // 16 tiles of 64 j

#define STAGE_KV(bi_, j0_)                                                       \
  do {                                                                           \
    _Pragma("unroll") for (int t = 0; t < 2; ++t) {                              \
      int c = t * 256 + tid;                                                     \
      int db = c >> 6, jj = c & 63;                                              \
      int sig = (jj & 0x33) | ((jj & 4) << 1) | ((jj & 8) >> 1);                 \
      char* lk = (char*)(&Ks[bi_][0]) + t * 4096 + (tid & 192) * 16;             \
      gload_lds16((const char*)(Kh + ((size_t)db * 4096 + (j0_) + sig) * 8), lk);\
      char* lv = (char*)(&Vt[bi_][0]) + t * 4096 + (tid & 192) * 16;             \
      gload_lds16((const char*)(Vh + ((size_t)(((j0_) >> 3) + db) * 64 + jj) * 8), lv); \
    }                                                                            \
  } while (0)

  // prologue: stage first tile into buf 0
  STAGE_KV(0, jbeg * 64);
  __syncthreads();

  for (int jt = jbeg; jt < jend; ++jt) {
    const int j0 = jt * 64;
    const int cur = jt & 1;  // jbeg is even (js*16)
    if (jt + 1 < jend) STAGE_KV(cur ^ 1, j0 + 64);

    const unsigned short* Kc = &Ks[cur][0];
    const unsigned short* Vc = &Vt[cur][0];

    // ---- seeds for BOTH halves (mask bias at sigma-mapped reg position) ----
    f32x16 s0, s1;
#pragma unroll
    for (int bq = 0; bq < 4; ++bq) {
      int boffm = j0 + ((bq & 1) << 2) + (hi << 3) + ((bq >> 1) << 4);
      f32x4 m4a = *(const f32x4*)&bb[boffm];
      f32x4 m4b = *(const f32x4*)&bb[boffm + 32];
#pragma unroll
      for (int e = 0; e < 4; ++e) {
        s0[bq * 4 + e] = m4a[e];
        s1[bq * 4 + e] = m4b[e];
      }
    }
    // ---- QK^T both halves (conflict-free A-frag reads) ----
    __builtin_amdgcn_s_setprio(1);
#pragma unroll
    for (int kc = 0; kc < 4; ++kc) {
      short8 kf0 = *(const short8*)((const char*)Kc + (2 * kc + hi) * 1024 + lq * 16);
      s0 = __builtin_amdgcn_mfma_f32_32x32x16_bf16(kf0, qf[kc], s0, 0, 0, 0);
    }
#pragma unroll
    for (int kc = 0; kc < 4; ++kc) {
      short8 kf1 = *(const short8*)((const char*)Kc + (2 * kc + hi) * 1024 + (32 + lq) * 16);
      s1 = __builtin_amdgcn_mfma_f32_32x32x16_bf16(kf1, qf[kc], s1, 0, 0, 0);
    }
    __builtin_amdgcn_s_setprio(0);
    // ---- softmax both halves (clamp via med3, exp2, 4-way den chains) ----
#pragma unroll
    for (int r = 0; r < 16; ++r) {
      float p = __builtin_amdgcn_exp2f(__builtin_amdgcn_fmed3f(s0[r], -CLIP2, CLIP2));
      den4[r & 3] += p;
      s0[r] = p;
    }
#pragma unroll
    for (int r = 0; r < 16; ++r) {
      float p = __builtin_amdgcn_exp2f(__builtin_amdgcn_fmed3f(s1[r], -CLIP2, CLIP2));
      den4[r & 3] += p;
      s1[r] = p;
    }
    // ---- pack both halves (truncate, 1 op/pair) ----
    unsigned int w0[8], w1[8];
#pragma unroll
    for (int i = 0; i < 8; ++i) w0[i] = pack_trunc(s0[i * 2], s0[i * 2 + 1]);
#pragma unroll
    for (int i = 0; i < 8; ++i) w1[i] = pack_trunc(s1[i * 2], s1[i * 2 + 1]);
    // ---- PV both halves ----
    __builtin_amdgcn_s_setprio(1);
#pragma unroll
    for (int kt = 0; kt < 2; ++kt) {
      union { unsigned int u[4]; short8 s; } pa;
      pa.u[0] = w0[kt * 4 + 0];
      pa.u[1] = w0[kt * 4 + 1];
      pa.u[2] = w0[kt * 4 + 2];
      pa.u[3] = w0[kt * 4 + 3];
#pragma unroll
      for (int dt = 0; dt < 2; ++dt) {
        short8 vf = *(const short8*)((const char*)Vc +
            (2 * kt + hi) * 1024 + (dt * 32 + lq) * 16);
        oacc[dt] = __builtin_amdgcn_mfma_f32_32x32x16_bf16(pa.s, vf, oacc[dt], 0, 0, 0);
      }
    }
#pragma unroll
    for (int kt = 0; kt < 2; ++kt) {
      union { unsigned int u[4]; short8 s; } pa;
      pa.u[0] = w1[kt * 4 + 0];
      pa.u[1] = w1[kt * 4 + 1];
      pa.u[2] = w1[kt * 4 + 2];
      pa.u[3] = w1[kt * 4 + 3];
#pragma unroll
      for (int dt = 0; dt < 2; ++dt) {
        short8 vf = *(const short8*)((const char*)Vc +
            (4 + 2 * kt + hi) * 1024 + (dt * 32 + lq) * 16);
        oacc[dt] = __builtin_amdgcn_mfma_f32_32x32x16_bf16(pa.s, vf, oacc[dt], 0, 0, 0);
      }
    }
    __builtin_amdgcn_s_setprio(0);
    // barrier: drains (already-landed) next-tile staging; protects buf reuse
    __syncthreads();
  }
#undef STAGE_KV

  // denominator: lanes l and l^32 hold disjoint j-sums for the same q
  float den = (den4[0] + den4[1]) + (den4[2] + den4[3]);
  den += __shfl_xor(den, 32);
  if (l < 32) denP[(((size_t)js * 64 + bh) * 1024) + q0 + l] = den;

  // numerator partials: q from reg index (PV C-layout), d from lane
#pragma unroll
  for (int dt = 0; dt < 2; ++dt)
#pragma unroll
    for (int r = 0; r < 16; ++r) {
      int q = q0 + (r & 3) + 8 * (r >> 2) + 4 * hi;
      int d = dt * 32 + lq;
      numP[((((size_t)js * 64 + bh) * 1024 + q) * 64) + d] = f2bf(oacc[dt][r]);
    }
}

// ---------------- combine j-split partials, divide, write Ob ----------------
__global__ __launch_bounds__(256) void attn_reduce_kernel(
    const unsigned short* __restrict__ numP, const float* __restrict__ denP,
    unsigned short* __restrict__ Ob) {
  int id = blockIdx.x * 256 + threadIdx.x;  // 0 .. 524287
  int d8 = id & 7;
  int q = (id >> 3) & 1023;
  int bh = id >> 13;
  int b = bh >> 4, h = bh & 15;
  float den = 0.f;
  float o[8] = {0.f, 0.f, 0.f, 0.f, 0.f, 0.f, 0.f, 0.f};
#pragma unroll
  for (int s = 0; s < 4; ++s) {
    const unsigned short* np =
        numP + ((((size_t)s * 64 + bh) * 1024 + q) * 64 + d8 * 8);
    u16x8 v = *(const u16x8*)np;
    den += denP[((size_t)s * 64 + bh) * 1024 + q];
#pragma unroll
    for (int e = 0; e < 8; ++e) o[e] += bf2f(v[e]);
  }
  float r = 1.0f / den;
  u16x8 outv;
#pragma unroll
  for (int e = 0; e < 8; ++e) outv[e] = f2bf(o[e] * r);
  *(u16x8*)&Ob[(((size_t)b * 1024 + q) * 1024) + h * 64 + d8 * 8] = outv;
}

// ---------------- launcher ----------------
extern "C" void kernel_launch(void* const* d_in, const int* in_sizes, int n_in,
                              void* d_out, int out_size, void* d_ws, size_t ws_size,
                              hipStream_t stream) {
  (void)in_sizes; (void)n_in; (void)out_size; (void)ws_size;
  const float* x    = (const float*)d_in[0];
  const float* ctx  = (const float*)d_in[1];
  const int*   mask = (const int*)d_in[2];
  const float* Wq   = (const float*)d_in[3];
  const float* Wkv  = (const float*)d_in[4];
  const float* Wo   = (const float*)d_in[5];
  const float* bo   = (const float*)d_in[6];
  float* out = (float*)d_out;

  char* ws = (char*)d_ws;
  const size_t MB = 1 << 20;
  // 0..40 MiB region is time-shared: {xb, cb} before attention; {numP, denP,
  // maskbias} after cb is consumed by the KV-GEMM (stream-ordered).
  unsigned short* numP = (unsigned short*)(ws + 0);        // 32 MiB : [4][64][1024][64] bf16
  float*          denP = (float*)(ws + 32 * MB);           // 1 MiB  : [4][64][1024] fp32
  float*          mbias= (float*)(ws + 33 * MB);           // 64 KiB : [4][4096] fp32
  unsigned short* xb   = (unsigned short*)(ws + 0);        // 8 MiB  : x bf16 [4096][1024]
  unsigned short* cb   = (unsigned short*)(ws + 8 * MB);   // 32 MiB : ctx bf16 [16384][1024]
  unsigned short* WqT  = (unsigned short*)(ws + 40 * MB);  // 2 MiB
  unsigned short* WkvT = (unsigned short*)(ws + 42 * MB);  // 4 MiB
  unsigned short* WoT  = (unsigned short*)(ws + 46 * MB);  // 2 MiB
  unsigned short* Qb   = (unsigned short*)(ws + 48 * MB);  // 8 MiB  : [bh][1024][64] (prescaled)
  unsigned short* K2   = (unsigned short*)(ws + 56 * MB);  // 32 MiB : [bh][d/8][4096][8]
  unsigned short* V2   = (unsigned short*)(ws + 88 * MB);  // 32 MiB : [bh][m/8][64][8]
  unsigned short* Ob   = (unsigned short*)(ws + 120 * MB); // 8 MiB  : [b][n][1024]

  cast_bf16_kernel<<<2048, 256, 0, stream>>>(x, xb, (4 * 1024 * 1024) / 8);
  cast_bf16_kernel<<<2048, 256, 0, stream>>>(ctx, cb, (16 * 1024 * 1024) / 8);
  transpose_cast_kernel<<<dim3(32, 32), 256, 0, stream>>>(Wq, WqT, 1024, 1024);
  transpose_cast_kernel<<<dim3(64, 32), 256, 0, stream>>>(Wkv, WkvT, 1024, 2048);
  transpose_cast_kernel<<<dim3(32, 32), 256, 0, stream>>>(Wo, WoT, 1024, 1024);

  gemm_bt_kernel<0><<<dim3(8, 32), 256, 0, stream>>>(xb, WqT, 4096, 1024, 1024,
                                                     Qb, (float*)nullptr,
                                                     (const float*)nullptr);
  gemm256_kv_kernel<<<dim3(8, 64), 512, 0, stream>>>(cb, WkvT, K2, V2);
  // mbias overlaps the (now-dead) cb region; launched after the KV-GEMM reads cb
  mask_bias_kernel<<<64, 256, 0, stream>>>(mask, mbias, 4 * 4096);
  attn_kernel<<<2048, 256, 0, stream>>>(K2, V2, Qb, mbias, numP, denP);
  attn_reduce_kernel<<<2048, 256, 0, stream>>>(numP, denP, Ob);
  gemm_bt_kernel<2><<<dim3(8, 32), 256, 0, stream>>>(Ob, WoT, 4096, 1024, 1024,
                                                     (unsigned short*)nullptr,
                                                     out, bo);
}

// Round 14
// 237.421 us; speedup vs baseline: 1.0310x; 1.0119x over previous
//
#include <hip/hip_runtime.h>
#include <hip/hip_bf16.h>

// Problem constants
// B=4, N=1024, M=4096, DQ=DC=1024, H=16, DH=64, INNER=1024, SCALE=0.125

typedef __attribute__((ext_vector_type(8))) short short8;          // 8 bf16 (MFMA A/B frag)
typedef __attribute__((ext_vector_type(8))) unsigned short u16x8;
typedef __attribute__((ext_vector_type(4))) float f32x4;
typedef __attribute__((ext_vector_type(16))) float f32x16;

static __device__ __forceinline__ void gload_lds16(const void* g, void* l) {
  __builtin_amdgcn_global_load_lds((const __attribute__((address_space(1))) void*)g,
                                   (__attribute__((address_space(3))) void*)l, 16, 0, 0);
}

static __device__ __forceinline__ unsigned short f2bf(float f) {
  __hip_bfloat16 h = __float2bfloat16(f);
  unsigned short u;
  __builtin_memcpy(&u, &h, 2);
  return u;
}

static __device__ __forceinline__ float bf2f(unsigned short u) {
  unsigned int x = (unsigned int)u << 16;
  float f;
  __builtin_memcpy(&f, &x, 4);
  return f;
}

// pack two positive floats to one u32 of 2 bf16 (TRUNCATE): 1 VALU op.
// Used only for P in attention: P>0, den kept fp32-exact.
static __device__ __forceinline__ unsigned int pack_trunc(float a, float b) {
  unsigned int ua, ub;
  __builtin_memcpy(&ua, &a, 4);
  __builtin_memcpy(&ub, &b, 4);
  return __builtin_amdgcn_perm(ua, ub, 0x03020706u);
}

// ---------------- cast fp32 -> bf16, 8 elems/thread ----------------
__global__ __launch_bounds__(256) void cast_bf16_kernel(const float* __restrict__ in,
                                                        unsigned short* __restrict__ out,
                                                        int n8) {
  int idx = blockIdx.x * 256 + threadIdx.x;
  int stride = gridDim.x * 256;
  for (int i = idx; i < n8; i += stride) {
    const float4* p = (const float4*)in + (size_t)i * 2;
    float4 a = p[0], b = p[1];
    u16x8 r;
    r[0] = f2bf(a.x); r[1] = f2bf(a.y); r[2] = f2bf(a.z); r[3] = f2bf(a.w);
    r[4] = f2bf(b.x); r[5] = f2bf(b.y); r[6] = f2bf(b.z); r[7] = f2bf(b.w);
    *((u16x8*)out + i) = r;
  }
}

// ---------------- mask -> fp32 additive bias (0 / -1e30) ----------------
__global__ __launch_bounds__(256) void mask_bias_kernel(const int* __restrict__ mask,
                                                        float* __restrict__ bias, int n) {
  int i = blockIdx.x * 256 + threadIdx.x;
  if (i < n) bias[i] = mask[i] ? 0.0f : -1e30f;
}

// ---------------- transpose + cast: W[K][N] fp32 -> Wt[N][K] bf16 ----------------
__global__ __launch_bounds__(256) void transpose_cast_kernel(const float* __restrict__ W,
                                                             unsigned short* __restrict__ Wt,
                                                             int K, int N) {
  __shared__ float tile[32][33];
  int n0 = blockIdx.x * 32, k0 = blockIdx.y * 32;
  int tx = threadIdx.x & 31, ty = threadIdx.x >> 5;
#pragma unroll
  for (int r = 0; r < 32; r += 8)
    tile[ty + r][tx] = W[(size_t)(k0 + ty + r) * N + n0 + tx];
  __syncthreads();
#pragma unroll
  for (int r = 0; r < 32; r += 8)
    Wt[(size_t)(n0 + ty + r) * K + k0 + tx] = f2bf(tile[tx][ty + r]);
}

// ---------------- 128^2 GEMM (m97 structure) for Q-proj and O-proj ----------------
// EPI 0: write Q layout [bh][n][64] bf16, PRESCALED by 0.125*log2(e)
// EPI 2: write fp32 outF[row*1024+col] = acc + bias[col]
template <int EPI>
__global__ __launch_bounds__(256, 2) void gemm_bt_kernel(
    const unsigned short* __restrict__ A, const unsigned short* __restrict__ Bt,
    int M, int N, int K,
    unsigned short* __restrict__ out0,
    float* __restrict__ outF, const float* __restrict__ bias) {
  __shared__ unsigned short As[128 * 64];
  __shared__ unsigned short Bs[128 * 64];
  const int tid = threadIdx.x;
  const int l = tid & 63;
  const int lq = l & 15, g = l >> 4;
  const int w = tid >> 6;
  const int wr = w >> 1, wc = w & 1;
  // XCD-chunked swizzle (nwg % 8 == 0 for all our grids)
  const int nwg = gridDim.x * gridDim.y;
  const int idl = blockIdx.y * gridDim.x + blockIdx.x;
  const int lin = (idl & 7) * (nwg >> 3) + (idl >> 3);
  const int m0 = (lin / gridDim.x) * 128, n0 = (lin % gridDim.x) * 128;

  f32x4 acc[4][4] = {};

  for (int k0 = 0; k0 < K; k0 += 64) {
    __syncthreads();
#pragma unroll
    for (int t = 0; t < 4; ++t) {
      int c = t * 256 + tid;
      int row = c >> 3, cb = c & 7;
      int srcoff = (cb * 16) ^ ((row & 7) << 4);
      char* la = (char*)As + t * 4096 + (tid & 192) * 16;  // wave-uniform base
      gload_lds16((const char*)(A + (size_t)(m0 + row) * K + k0) + srcoff, la);
      char* lb = (char*)Bs + t * 4096 + (tid & 192) * 16;
      gload_lds16((const char*)(Bt + (size_t)(n0 + row) * K + k0) + srcoff, lb);
    }
    __syncthreads();
#pragma unroll
    for (int ks = 0; ks < 2; ++ks) {
      short8 af[4], bfr[4];
#pragma unroll
      for (int mt = 0; mt < 4; ++mt) {
        int row = wr * 64 + mt * 16 + lq;
        af[mt] = *(const short8*)&As[row * 64 + ((ks * 32 + g * 8) ^ ((row & 7) << 3))];
      }
#pragma unroll
      for (int nt = 0; nt < 4; ++nt) {
        int row = wc * 64 + nt * 16 + lq;
        bfr[nt] = *(const short8*)&Bs[row * 64 + ((ks * 32 + g * 8) ^ ((row & 7) << 3))];
      }
#pragma unroll
      for (int mt = 0; mt < 4; ++mt)
#pragma unroll
        for (int nt = 0; nt < 4; ++nt)
          acc[mt][nt] =
              __builtin_amdgcn_mfma_f32_16x16x32_bf16(af[mt], bfr[nt], acc[mt][nt], 0, 0, 0);
    }
  }

#pragma unroll
  for (int mt = 0; mt < 4; ++mt) {
#pragma unroll
    for (int nt = 0; nt < 4; ++nt) {
#pragma unroll
      for (int r = 0; r < 4; ++r) {
        int row = m0 + wr * 64 + mt * 16 + g * 4 + r;
        int col = n0 + wc * 64 + nt * 16 + lq;
        float v = acc[mt][nt][r];
        if (EPI == 0) {
          int b = row >> 10, nq = row & 1023;
          int h = col >> 6, d = col & 63;
          // fold softmax scale (0.125 * log2 e) into Q
          out0[(((size_t)(b * 16 + h)) * 1024 + nq) * 64 + d] =
              f2bf(v * 0.18033688011112042f);
        } else {
          outF[(size_t)row * 1024 + col] = v + bias[col];
        }
      }
    }
  }
}

// ---------------- 256^2 8-phase KV GEMM (fine interleave, counted vmcnt) ----------------
// C[16384, 2048] = cb * WkvT^T, BK=64, 16 K-tiles, 2 K-tiles/iteration.
// LDS: 2 slots x {A: 2 ks-halves x 16KB, B: same} = 128 KB. 8 waves (2Mx4N).
// Phase = (ks-half, nf-pair) quadrant: {2 B-frag reads (+8 A reads on ks
// change), 1 half-tile stage (2 gload_lds), barrier, lgkmcnt(0)+sched_barrier,
// setprio(1), 16 MFMA, setprio(0), [vmcnt gate at q3], barrier}.
// K-HALF half-tiles die after 2 phases -> refilled 2-6 phases ahead:
//   q0/q1 of kt stage (kt+1)'s k1-halves (into slot (kt+1)&1: old k1 dead)
//   q2/q3 of kt stage (kt+2)'s k0-halves (into slot kt&1: k0 just consumed)
// Gate vmcnt(4) at end of q3: newest 2 half-tiles (4 loads) may stay in
// flight; everything the next K-tile reads is retired. Staging is
// wave-symmetric so per-wave vmcnt + barrier covers all writers.
// LDS layout (pair-interleaved, 2-way=free on every 16-lane frag phase):
//   element (row,k): p=row>>1, pos=((row&1)*4 + ((k_local)>>3)) ^ (p&7),
//   byte = slot*65536 + (B?32768:0) + ks*16384 + p*128 + pos*16 + (k&7)*2.
// EPI: cols<1024 -> K2[bh][d>>3][m][d&7]; cols>=1024 -> V2[bh][m>>3][d][m&7]
__global__ __launch_bounds__(512, 2) void gemm256_kv8_kernel(
    const unsigned short* __restrict__ A, const unsigned short* __restrict__ Bt,
    unsigned short* __restrict__ K2out, unsigned short* __restrict__ V2out) {
  __shared__ unsigned short lds[65536];  // 128 KB
  const int tid = threadIdx.x;
  const int l = tid & 63;
  const int lq = l & 15, g = l >> 4;
  const int w = tid >> 6;            // 0..7
  const int wm = w >> 2, wn = w & 3;
  // XCD-chunked swizzle (nwg = 512)
  const int nwg = gridDim.x * gridDim.y;
  const int idl = blockIdx.y * gridDim.x + blockIdx.x;
  const int lin = (idl & 7) * (nwg >> 3) + (idl >> 3);
  const int m0 = (lin / gridDim.x) * 256;
  const int n0 = (lin % gridDim.x) * 256;

  // staging source decode (inverse of LDS layout), per thread, j=0/1
  int row0, gg0, row1, gg1;
  { int u = tid;       int p = u >> 3; int t = (u & 7) ^ (p & 7); row0 = 2 * p + (t >> 2); gg0 = t & 3; }
  { int u = 512 + tid; int p = u >> 3; int t = (u & 7) ^ (p & 7); row1 = 2 * p + (t >> 2); gg1 = t & 3; }
  const unsigned short* sA0 = A  + (size_t)(m0 + row0) * 1024 + gg0 * 8;
  const unsigned short* sA1 = A  + (size_t)(m0 + row1) * 1024 + gg1 * 8;
  const unsigned short* sB0 = Bt + (size_t)(n0 + row0) * 1024 + gg0 * 8;
  const unsigned short* sB1 = Bt + (size_t)(n0 + row1) * 1024 + gg1 * 8;
  const int wub = (tid & 448) * 16;  // wave-uniform LDS dest base (lane x16 added by HW)

  // loop-invariant frag byte offsets
  int aoffb[8], boffb[4];
#pragma unroll
  for (int mf = 0; mf < 8; ++mf) {
    int row = wm * 128 + mf * 16 + lq;
    int p = row >> 1;
    int pos = (((row & 1) << 2) + g) ^ (p & 7);
    aoffb[mf] = p * 128 + pos * 16;
  }
#pragma unroll
  for (int nf = 0; nf < 4; ++nf) {
    int row = wn * 64 + nf * 16 + lq;
    int p = row >> 1;
    int pos = (((row & 1) << 2) + g) ^ (p & 7);
    boffb[nf] = 32768 + p * 128 + pos * 16;
  }

  f32x4 acc[8][4] = {};
  short8 af[8];

#define STGA(kt_, ks_, slot_)                                                      \
  do {                                                                             \
    gload_lds16(sA0 + (kt_) * 64 + (ks_) * 32,                                     \
                (char*)lds + (slot_) * 65536 + (ks_) * 16384 + wub);               \
    gload_lds16(sA1 + (kt_) * 64 + (ks_) * 32,                                     \
                (char*)lds + (slot_) * 65536 + (ks_) * 16384 + 8192 + wub);        \
  } while (0)
#define STGB(kt_, ks_, slot_)                                                      \
  do {                                                                             \
    gload_lds16(sB0 + (kt_) * 64 + (ks_) * 32,                                     \
                (char*)lds + (slot_) * 65536 + 32768 + (ks_) * 16384 + wub);       \
    gload_lds16(sB1 + (kt_) * 64 + (ks_) * 32,                                     \
                (char*)lds + (slot_) * 65536 + 32768 + (ks_) * 16384 + 8192 + wub);\
  } while (0)

#define PHASE(slot_, ks_, nfp_, RELA_, STGSTMT, GATESTMT)                          \
  do {                                                                             \
    const char* base_ = (const char*)lds + (slot_) * 65536 + (ks_) * 16384;        \
    if (RELA_) {                                                                   \
      _Pragma("unroll") for (int mf_ = 0; mf_ < 8; ++mf_)                          \
          af[mf_] = *(const short8*)(base_ + aoffb[mf_]);                          \
    }                                                                              \
    short8 bf0_ = *(const short8*)(base_ + boffb[2 * (nfp_) + 0]);                 \
    short8 bf1_ = *(const short8*)(base_ + boffb[2 * (nfp_) + 1]);                 \
    STGSTMT;                                                                       \
    __builtin_amdgcn_s_barrier();                                                  \
    asm volatile("s_waitcnt lgkmcnt(0)" ::: "memory");                             \
    __builtin_amdgcn_sched_barrier(0);                                             \
    __builtin_amdgcn_s_setprio(1);                                                 \
    _Pragma("unroll") for (int mf_ = 0; mf_ < 8; ++mf_) {                          \
      acc[mf_][2 * (nfp_) + 0] = __builtin_amdgcn_mfma_f32_16x16x32_bf16(          \
          af[mf_], bf0_, acc[mf_][2 * (nfp_) + 0], 0, 0, 0);                       \
      acc[mf_][2 * (nfp_) + 1] = __builtin_amdgcn_mfma_f32_16x16x32_bf16(          \
          af[mf_], bf1_, acc[mf_][2 * (nfp_) + 1], 0, 0, 0);                       \
    }                                                                              \
    __builtin_amdgcn_s_setprio(0);                                                 \
    GATESTMT;                                                                      \
    __builtin_amdgcn_s_barrier();                                                  \
  } while (0)

#define GATE4 asm volatile("s_waitcnt vmcnt(4)" ::: "memory")
#define GATE0 asm volatile("s_waitcnt vmcnt(0)" ::: "memory")
#define NOSTMT do {} while (0)

  // prologue: kt0 fully + kt1's k0 halves; gate so kt0 is resident
  STGA(0, 0, 0); STGA(0, 1, 0); STGB(0, 0, 0); STGB(0, 1, 0);
  STGA(1, 0, 1); STGB(1, 0, 1);
  GATE4;
  __builtin_amdgcn_s_barrier();

  // steady iterations: kt = 2it (slot0), 2it+1 (slot1), it = 0..6 (kt 0..13)
  for (int it = 0; it < 7; ++it) {
    const int kt = 2 * it;
    // kt (slot 0)
    PHASE(0, 0, 0, 1, STGA(kt + 1, 1, 1), NOSTMT);
    PHASE(0, 0, 1, 0, STGB(kt + 1, 1, 1), NOSTMT);
    PHASE(0, 1, 0, 1, STGA(kt + 2, 0, 0), NOSTMT);
    PHASE(0, 1, 1, 0, STGB(kt + 2, 0, 0), GATE4);
    // kt+1 (slot 1)
    PHASE(1, 0, 0, 1, STGA(kt + 2, 1, 0), NOSTMT);
    PHASE(1, 0, 1, 0, STGB(kt + 2, 1, 0), NOSTMT);
    PHASE(1, 1, 0, 1, STGA(kt + 3, 0, 1), NOSTMT);
    PHASE(1, 1, 1, 0, STGB(kt + 3, 0, 1), GATE4);
  }
  // tail: kt = 14 (slot 0) stages only kt15's k1; drain at its end
  PHASE(0, 0, 0, 1, STGA(15, 1, 1), NOSTMT);
  PHASE(0, 0, 1, 0, STGB(15, 1, 1), NOSTMT);
  PHASE(0, 1, 0, 1, NOSTMT, NOSTMT);
  PHASE(0, 1, 1, 0, NOSTMT, GATE0);
  // kt = 15 (slot 1): no staging, no gates
  PHASE(1, 0, 0, 1, NOSTMT, NOSTMT);
  PHASE(1, 0, 1, 0, NOSTMT, NOSTMT);
  PHASE(1, 1, 0, 1, NOSTMT, NOSTMT);
  PHASE(1, 1, 1, 0, NOSTMT, NOSTMT);

#undef PHASE
#undef STGA
#undef STGB
#undef GATE4
#undef GATE0
#undef NOSTMT

  // epilogue (round-12 verified): K2/V2 scatter
#pragma unroll
  for (int mt = 0; mt < 8; ++mt) {
#pragma unroll
    for (int nt = 0; nt < 4; ++nt) {
      int col = n0 + wn * 64 + nt * 16 + lq;
      int rowb = m0 + wm * 128 + mt * 16 + g * 4;
      int b = rowb >> 12, mm = rowb & 4095;
      if (col < 1024) {
        int h = col >> 6, d = col & 63;
#pragma unroll
        for (int r = 0; r < 4; ++r) {
          size_t off =
              (((size_t)(b * 16 + h) * 8 + (d >> 3)) * 4096 + (mm + r)) * 8 + (d & 7);
          K2out[off] = f2bf(acc[mt][nt][r]);
        }
      } else {
        int hv = col - 1024;
        int h = hv >> 6, d = hv & 63;
        ushort4 pk;
        pk.x = f2bf(acc[mt][nt][0]);
        pk.y = f2bf(acc[mt][nt][1]);
        pk.z = f2bf(acc[mt][nt][2]);
        pk.w = f2bf(acc[mt][nt][3]);
        size_t off = (((size_t)(b * 16 + h) * 512 + (mm >> 3)) * 64 + d) * 8 + (mm & 7);
        *(ushort4*)&V2out[off] = pk;
      }
    }
  }
}

// ---------------- fused attention (two-phase halves, in-register P) ----------------
// Round-13 verified: conflict-free d-block-major LDS, sigma-permuted K,
// in-register P, zero-shuffle PV, mask as MFMA C-seed, Q prescaled, KVBLK=64
// dbuf, two-phase halves, 4-way den chains, truncate pack.
__global__ __launch_bounds__(256, 3) void attn_kernel(
    const unsigned short* __restrict__ K2, const unsigned short* __restrict__ V2,
    const unsigned short* __restrict__ Q, const float* __restrict__ maskb,
    unsigned short* __restrict__ numP, float* __restrict__ denP) {
  __shared__ unsigned short Ks[2][8 * 64 * 8];  // [buf][db][jj (sigma'd)][8 d-elems]
  __shared__ unsigned short Vt[2][8 * 64 * 8];  // [buf][jb][d][8 j-elems]

  const int tid = threadIdx.x;
  const int l = tid & 63, w = tid >> 6;
  const int lq = l & 31;  // q within the wave's 32-row block / row index
  const int hi = l >> 5;  // lane half

  // XCD-affine decode: id&7 = XCD; 8 consecutive same-XCD blocks share (bh,js)
  const int id = blockIdx.x;
  const int xcd = id & 7;
  const int kk = id >> 3;
  const int qi = kk & 7;
  const int pr = xcd * 32 + (kk >> 3);
  const int bh = pr & 63, js = pr >> 6;
  const int b = bh >> 4;
  const int q0 = qi * 128 + w * 32;

  const unsigned short* Qh = Q + (size_t)bh * 1024 * 64;
  const unsigned short* Kh = K2 + (size_t)bh * 8 * 4096 * 8;   // [db][m][8]
  const unsigned short* Vh = V2 + (size_t)bh * 512 * 64 * 8;   // [jb][d][8]
  const float* bb = maskb + b * 4096;

  const float CLIP2 = 7.213475204444817f;  // 5 * log2(e)

  // Q fragments (B-operand): lane holds Q[q0+lq][kc*16 + hi*8 + e], prescaled
  short8 qf[4];
#pragma unroll
  for (int kc = 0; kc < 4; ++kc)
    qf[kc] = *(const short8*)&Qh[(size_t)(q0 + lq) * 64 + kc * 16 + hi * 8];

  f32x16 oacc[2] = {};
  float den4[4] = {};

  const int jbeg = js * 16, jend = jbeg + 16;  // 16 tiles of 64 j

#define STAGE_KV(bi_, j0_)                                                       \
  do {                                                                           \
    _Pragma("unroll") for (int t = 0; t < 2; ++t) {                              \
      int c = t * 256 + tid;                                                     \
      int db = c >> 6, jj = c & 63;                                              \
      int sig = (jj & 0x33) | ((jj & 4) << 1) | ((jj & 8) >> 1);                 \
      char* lk = (char*)(&Ks[bi_][0]) + t * 4096 + (tid & 192) * 16;             \
      gload_lds16((const char*)(Kh + ((size_t)db * 4096 + (j0_) + sig) * 8), lk);\
      char* lv = (char*)(&Vt[bi_][0]) + t * 4096 + (tid & 192) * 16;             \
      gload_lds16((const char*)(Vh + ((size_t)(((j0_) >> 3) + db) * 64 + jj) * 8), lv); \
    }                                                                            \
  } while (0)

  // prologue: stage first tile into buf 0
  STAGE_KV(0, jbeg * 64);
  __syncthreads();

  for (int jt = jbeg; jt < jend; ++jt) {
    const int j0 = jt * 64;
    const int cur = jt & 1;  // jbeg is even (js*16)
    if (jt + 1 < jend) STAGE_KV(cur ^ 1, j0 + 64);

    const unsigned short* Kc = &Ks[cur][0];
    const unsigned short* Vc = &Vt[cur][0];

    // ---- seeds for BOTH halves (mask bias at sigma-mapped reg position) ----
    f32x16 s0, s1;
#pragma unroll
    for (int bq = 0; bq < 4; ++bq) {
      int boffm = j0 + ((bq & 1) << 2) + (hi << 3) + ((bq >> 1) << 4);
      f32x4 m4a = *(const f32x4*)&bb[boffm];
      f32x4 m4b = *(const f32x4*)&bb[boffm + 32];
#pragma unroll
      for (int e = 0; e < 4; ++e) {
        s0[bq * 4 + e] = m4a[e];
        s1[bq * 4 + e] = m4b[e];
      }
    }
    // ---- QK^T both halves (conflict-free A-frag reads) ----
    __builtin_amdgcn_s_setprio(1);
#pragma unroll
    for (int kc = 0; kc < 4; ++kc) {
      short8 kf0 = *(const short8*)((const char*)Kc + (2 * kc + hi) * 1024 + lq * 16);
      s0 = __builtin_amdgcn_mfma_f32_32x32x16_bf16(kf0, qf[kc], s0, 0, 0, 0);
    }
#pragma unroll
    for (int kc = 0; kc < 4; ++kc) {
      short8 kf1 = *(const short8*)((const char*)Kc + (2 * kc + hi) * 1024 + (32 + lq) * 16);
      s1 = __builtin_amdgcn_mfma_f32_32x32x16_bf16(kf1, qf[kc], s1, 0, 0, 0);
    }
    __builtin_amdgcn_s_setprio(0);
    // ---- softmax both halves (clamp via med3, exp2, 4-way den chains) ----
#pragma unroll
    for (int r = 0; r < 16; ++r) {
      float p = __builtin_amdgcn_exp2f(__builtin_amdgcn_fmed3f(s0[r], -CLIP2, CLIP2));
      den4[r & 3] += p;
      s0[r] = p;
    }
#pragma unroll
    for (int r = 0; r < 16; ++r) {
      float p = __builtin_amdgcn_exp2f(__builtin_amdgcn_fmed3f(s1[r], -CLIP2, CLIP2));
      den4[r & 3] += p;
      s1[r] = p;
    }
    // ---- pack both halves (truncate, 1 op/pair) ----
    unsigned int w0[8], w1[8];
#pragma unroll
    for (int i = 0; i < 8; ++i) w0[i] = pack_trunc(s0[i * 2], s0[i * 2 + 1]);
#pragma unroll
    for (int i = 0; i < 8; ++i) w1[i] = pack_trunc(s1[i * 2], s1[i * 2 + 1]);
    // ---- PV both halves ----
    __builtin_amdgcn_s_setprio(1);
#pragma unroll
    for (int kt = 0; kt < 2; ++kt) {
      union { unsigned int u[4]; short8 s; } pa;
      pa.u[0] = w0[kt * 4 + 0];
      pa.u[1] = w0[kt * 4 + 1];
      pa.u[2] = w0[kt * 4 + 2];
      pa.u[3] = w0[kt * 4 + 3];
#pragma unroll
      for (int dt = 0; dt < 2; ++dt) {
        short8 vf = *(const short8*)((const char*)Vc +
            (2 * kt + hi) * 1024 + (dt * 32 + lq) * 16);
        oacc[dt] = __builtin_amdgcn_mfma_f32_32x32x16_bf16(pa.s, vf, oacc[dt], 0, 0, 0);
      }
    }
#pragma unroll
    for (int kt = 0; kt < 2; ++kt) {
      union { unsigned int u[4]; short8 s; } pa;
      pa.u[0] = w1[kt * 4 + 0];
      pa.u[1] = w1[kt * 4 + 1];
      pa.u[2] = w1[kt * 4 + 2];
      pa.u[3] = w1[kt * 4 + 3];
#pragma unroll
      for (int dt = 0; dt < 2; ++dt) {
        short8 vf = *(const short8*)((const char*)Vc +
            (4 + 2 * kt + hi) * 1024 + (dt * 32 + lq) * 16);
        oacc[dt] = __builtin_amdgcn_mfma_f32_32x32x16_bf16(pa.s, vf, oacc[dt], 0, 0, 0);
      }
    }
    __builtin_amdgcn_s_setprio(0);
    // barrier: drains (already-landed) next-tile staging; protects buf reuse
    __syncthreads();
  }
#undef STAGE_KV

  // denominator: lanes l and l^32 hold disjoint j-sums for the same q
  float den = (den4[0] + den4[1]) + (den4[2] + den4[3]);
  den += __shfl_xor(den, 32);
  if (l < 32) denP[(((size_t)js * 64 + bh) * 1024) + q0 + l] = den;

  // numerator partials: q from reg index (PV C-layout), d from lane
#pragma unroll
  for (int dt = 0; dt < 2; ++dt)
#pragma unroll
    for (int r = 0; r < 16; ++r) {
      int q = q0 + (r & 3) + 8 * (r >> 2) + 4 * hi;
      int d = dt * 32 + lq;
      numP[((((size_t)js * 64 + bh) * 1024 + q) * 64) + d] = f2bf(oacc[dt][r]);
    }
}

// ---------------- combine j-split partials, divide, write Ob ----------------
__global__ __launch_bounds__(256) void attn_reduce_kernel(
    const unsigned short* __restrict__ numP, const float* __restrict__ denP,
    unsigned short* __restrict__ Ob) {
  int id = blockIdx.x * 256 + threadIdx.x;  // 0 .. 524287
  int d8 = id & 7;
  int q = (id >> 3) & 1023;
  int bh = id >> 13;
  int b = bh >> 4, h = bh & 15;
  float den = 0.f;
  float o[8] = {0.f, 0.f, 0.f, 0.f, 0.f, 0.f, 0.f, 0.f};
#pragma unroll
  for (int s = 0; s < 4; ++s) {
    const unsigned short* np =
        numP + ((((size_t)s * 64 + bh) * 1024 + q) * 64 + d8 * 8);
    u16x8 v = *(const u16x8*)np;
    den += denP[((size_t)s * 64 + bh) * 1024 + q];
#pragma unroll
    for (int e = 0; e < 8; ++e) o[e] += bf2f(v[e]);
  }
  float r = 1.0f / den;
  u16x8 outv;
#pragma unroll
  for (int e = 0; e < 8; ++e) outv[e] = f2bf(o[e] * r);
  *(u16x8*)&Ob[(((size_t)b * 1024 + q) * 1024) + h * 64 + d8 * 8] = outv;
}

// ---------------- launcher ----------------
extern "C" void kernel_launch(void* const* d_in, const int* in_sizes, int n_in,
                              void* d_out, int out_size, void* d_ws, size_t ws_size,
                              hipStream_t stream) {
  (void)in_sizes; (void)n_in; (void)out_size; (void)ws_size;
  const float* x    = (const float*)d_in[0];
  const float* ctx  = (const float*)d_in[1];
  const int*   mask = (const int*)d_in[2];
  const float* Wq   = (const float*)d_in[3];
  const float* Wkv  = (const float*)d_in[4];
  const float* Wo   = (const float*)d_in[5];
  const float* bo   = (const float*)d_in[6];
  float* out = (float*)d_out;

  char* ws = (char*)d_ws;
  const size_t MB = 1 << 20;
  // 0..40 MiB region is time-shared: {xb, cb} before attention; {numP, denP,
  // maskbias} after cb is consumed by the KV-GEMM (stream-ordered).
  unsigned short* numP = (unsigned short*)(ws + 0);        // 32 MiB : [4][64][1024][64] bf16
  float*          denP = (float*)(ws + 32 * MB);           // 1 MiB  : [4][64][1024] fp32
  float*          mbias= (float*)(ws + 33 * MB);           // 64 KiB : [4][4096] fp32
  unsigned short* xb   = (unsigned short*)(ws + 0);        // 8 MiB  : x bf16 [4096][1024]
  unsigned short* cb   = (unsigned short*)(ws + 8 * MB);   // 32 MiB : ctx bf16 [16384][1024]
  unsigned short* WqT  = (unsigned short*)(ws + 40 * MB);  // 2 MiB
  unsigned short* WkvT = (unsigned short*)(ws + 42 * MB);  // 4 MiB
  unsigned short* WoT  = (unsigned short*)(ws + 46 * MB);  // 2 MiB
  unsigned short* Qb   = (unsigned short*)(ws + 48 * MB);  // 8 MiB  : [bh][1024][64] (prescaled)
  unsigned short* K2   = (unsigned short*)(ws + 56 * MB);  // 32 MiB : [bh][d/8][4096][8]
  unsigned short* V2   = (unsigned short*)(ws + 88 * MB);  // 32 MiB : [bh][m/8][64][8]
  unsigned short* Ob   = (unsigned short*)(ws + 120 * MB); // 8 MiB  : [b][n][1024]

  cast_bf16_kernel<<<2048, 256, 0, stream>>>(x, xb, (4 * 1024 * 1024) / 8);
  cast_bf16_kernel<<<2048, 256, 0, stream>>>(ctx, cb, (16 * 1024 * 1024) / 8);
  transpose_cast_kernel<<<dim3(32, 32), 256, 0, stream>>>(Wq, WqT, 1024, 1024);
  transpose_cast_kernel<<<dim3(64, 32), 256, 0, stream>>>(Wkv, WkvT, 1024, 2048);
  transpose_cast_kernel<<<dim3(32, 32), 256, 0, stream>>>(Wo, WoT, 1024, 1024);

  gemm_bt_kernel<0><<<dim3(8, 32), 256, 0, stream>>>(xb, WqT, 4096, 1024, 1024,
                                                     Qb, (float*)nullptr,
                                                     (const float*)nullptr);
  gemm256_kv8_kernel<<<dim3(8, 64), 512, 0, stream>>>(cb, WkvT, K2, V2);
  // mbias overlaps the (now-dead) cb region; launched after the KV-GEMM reads cb
  mask_bias_kernel<<<64, 256, 0, stream>>>(mask, mbias, 4 * 4096);
  attn_kernel<<<2048, 256, 0, stream>>>(K2, V2, Qb, mbias, numP, denP);
  attn_reduce_kernel<<<2048, 256, 0, stream>>>(numP, denP, Ob);
  gemm_bt_kernel<2><<<dim3(8, 32), 256, 0, stream>>>(Ob, WoT, 4096, 1024, 1024,
                                                     (unsigned short*)nullptr,
                                                     out, bo);
}

// Round 15
// 237.320 us; speedup vs baseline: 1.0315x; 1.0004x over previous
//
#include <hip/hip_runtime.h>
#include <hip/hip_bf16.h>

// Problem constants
// B=4, N=1024, M=4096, DQ=DC=1024, H=16, DH=64, INNER=1024, SCALE=0.125

typedef __attribute__((ext_vector_type(8))) short short8;          // 8 bf16 (MFMA A/B frag)
typedef __attribute__((ext_vector_type(8))) unsigned short u16x8;
typedef __attribute__((ext_vector_type(4))) float f32x4;
typedef __attribute__((ext_vector_type(16))) float f32x16;

static __device__ __forceinline__ void gload_lds16(const void* g, void* l) {
  __builtin_amdgcn_global_load_lds((const __attribute__((address_space(1))) void*)g,
                                   (__attribute__((address_space(3))) void*)l, 16, 0, 0);
}

static __device__ __forceinline__ unsigned short f2bf(float f) {
  __hip_bfloat16 h = __float2bfloat16(f);
  unsigned short u;
  __builtin_memcpy(&u, &h, 2);
  return u;
}

static __device__ __forceinline__ float bf2f(unsigned short u) {
  unsigned int x = (unsigned int)u << 16;
  float f;
  __builtin_memcpy(&f, &x, 4);
  return f;
}

// pack two positive floats to one u32 of 2 bf16 (TRUNCATE): 1 VALU op.
// Used only for P in attention: P>0, den kept fp32-exact.
static __device__ __forceinline__ unsigned int pack_trunc(float a, float b) {
  unsigned int ua, ub;
  __builtin_memcpy(&ua, &a, 4);
  __builtin_memcpy(&ub, &b, 4);
  return __builtin_amdgcn_perm(ua, ub, 0x03020706u);
}

// ---------------- cast fp32 -> bf16, 8 elems/thread ----------------
__global__ __launch_bounds__(256) void cast_bf16_kernel(const float* __restrict__ in,
                                                        unsigned short* __restrict__ out,
                                                        int n8) {
  int idx = blockIdx.x * 256 + threadIdx.x;
  int stride = gridDim.x * 256;
  for (int i = idx; i < n8; i += stride) {
    const float4* p = (const float4*)in + (size_t)i * 2;
    float4 a = p[0], b = p[1];
    u16x8 r;
    r[0] = f2bf(a.x); r[1] = f2bf(a.y); r[2] = f2bf(a.z); r[3] = f2bf(a.w);
    r[4] = f2bf(b.x); r[5] = f2bf(b.y); r[6] = f2bf(b.z); r[7] = f2bf(b.w);
    *((u16x8*)out + i) = r;
  }
}

// ---------------- mask -> fp32 additive bias (0 / -1e30) ----------------
__global__ __launch_bounds__(256) void mask_bias_kernel(const int* __restrict__ mask,
                                                        float* __restrict__ bias, int n) {
  int i = blockIdx.x * 256 + threadIdx.x;
  if (i < n) bias[i] = mask[i] ? 0.0f : -1e30f;
}

// ---------------- transpose + cast: W[K][N] fp32 -> Wt[N][K] bf16 ----------------
__global__ __launch_bounds__(256) void transpose_cast_kernel(const float* __restrict__ W,
                                                             unsigned short* __restrict__ Wt,
                                                             int K, int N) {
  __shared__ float tile[32][33];
  int n0 = blockIdx.x * 32, k0 = blockIdx.y * 32;
  int tx = threadIdx.x & 31, ty = threadIdx.x >> 5;
#pragma unroll
  for (int r = 0; r < 32; r += 8)
    tile[ty + r][tx] = W[(size_t)(k0 + ty + r) * N + n0 + tx];
  __syncthreads();
#pragma unroll
  for (int r = 0; r < 32; r += 8)
    Wt[(size_t)(n0 + ty + r) * K + k0 + tx] = f2bf(tile[tx][ty + r]);
}

// ---------------- 128^2 GEMM (m97 structure) for Q-proj and O-proj ----------------
// EPI 0: write Q layout [bh][n][64] bf16, PRESCALED by 0.125*log2(e)
// EPI 2: write fp32 outF[row*1024+col] = acc + bias[col]
template <int EPI>
__global__ __launch_bounds__(256, 2) void gemm_bt_kernel(
    const unsigned short* __restrict__ A, const unsigned short* __restrict__ Bt,
    int M, int N, int K,
    unsigned short* __restrict__ out0,
    float* __restrict__ outF, const float* __restrict__ bias) {
  __shared__ unsigned short As[128 * 64];
  __shared__ unsigned short Bs[128 * 64];
  const int tid = threadIdx.x;
  const int l = tid & 63;
  const int lq = l & 15, g = l >> 4;
  const int w = tid >> 6;
  const int wr = w >> 1, wc = w & 1;
  // XCD-chunked swizzle (nwg % 8 == 0 for all our grids)
  const int nwg = gridDim.x * gridDim.y;
  const int idl = blockIdx.y * gridDim.x + blockIdx.x;
  const int lin = (idl & 7) * (nwg >> 3) + (idl >> 3);
  const int m0 = (lin / gridDim.x) * 128, n0 = (lin % gridDim.x) * 128;

  f32x4 acc[4][4] = {};

  for (int k0 = 0; k0 < K; k0 += 64) {
    __syncthreads();
#pragma unroll
    for (int t = 0; t < 4; ++t) {
      int c = t * 256 + tid;
      int row = c >> 3, cb = c & 7;
      int srcoff = (cb * 16) ^ ((row & 7) << 4);
      char* la = (char*)As + t * 4096 + (tid & 192) * 16;  // wave-uniform base
      gload_lds16((const char*)(A + (size_t)(m0 + row) * K + k0) + srcoff, la);
      char* lb = (char*)Bs + t * 4096 + (tid & 192) * 16;
      gload_lds16((const char*)(Bt + (size_t)(n0 + row) * K + k0) + srcoff, lb);
    }
    __syncthreads();
#pragma unroll
    for (int ks = 0; ks < 2; ++ks) {
      short8 af[4], bfr[4];
#pragma unroll
      for (int mt = 0; mt < 4; ++mt) {
        int row = wr * 64 + mt * 16 + lq;
        af[mt] = *(const short8*)&As[row * 64 + ((ks * 32 + g * 8) ^ ((row & 7) << 3))];
      }
#pragma unroll
      for (int nt = 0; nt < 4; ++nt) {
        int row = wc * 64 + nt * 16 + lq;
        bfr[nt] = *(const short8*)&Bs[row * 64 + ((ks * 32 + g * 8) ^ ((row & 7) << 3))];
      }
#pragma unroll
      for (int mt = 0; mt < 4; ++mt)
#pragma unroll
        for (int nt = 0; nt < 4; ++nt)
          acc[mt][nt] =
              __builtin_amdgcn_mfma_f32_16x16x32_bf16(af[mt], bfr[nt], acc[mt][nt], 0, 0, 0);
    }
  }

#pragma unroll
  for (int mt = 0; mt < 4; ++mt) {
#pragma unroll
    for (int nt = 0; nt < 4; ++nt) {
#pragma unroll
      for (int r = 0; r < 4; ++r) {
        int row = m0 + wr * 64 + mt * 16 + g * 4 + r;
        int col = n0 + wc * 64 + nt * 16 + lq;
        float v = acc[mt][nt][r];
        if (EPI == 0) {
          int b = row >> 10, nq = row & 1023;
          int h = col >> 6, d = col & 63;
          // fold softmax scale (0.125 * log2 e) into Q
          out0[(((size_t)(b * 16 + h)) * 1024 + nq) * 64 + d] =
              f2bf(v * 0.18033688011112042f);
        } else {
          outF[(size_t)row * 1024 + col] = v + bias[col];
        }
      }
    }
  }
}

// ---------------- 256^2 8-phase KV GEMM (fine interleave, counted vmcnt) ----------------
// C[16384, 2048] = cb * WkvT^T, BK=64, 16 K-tiles, 2 K-tiles/iteration.
// LDS: 2 slots x {A: 2 ks-halves x 16KB, B: same} = 128 KB. 8 waves (2Mx4N).
// Phase = (ks-half, nf-pair) quadrant: {2 B-frag reads (+8 A reads on ks
// change), 1 half-tile stage (2 gload_lds), barrier, lgkmcnt(0)+sched_barrier,
// setprio(1), 16 MFMA, setprio(0), [vmcnt gate at q3], barrier}.
// K-HALF half-tiles die after 2 phases -> refilled 2-6 phases ahead:
//   q0/q1 of kt stage (kt+1)'s k1-halves (into slot (kt+1)&1: old k1 dead)
//   q2/q3 of kt stage (kt+2)'s k0-halves (into slot kt&1: k0 just consumed)
// Gate vmcnt(4) at end of q3: newest 2 half-tiles (4 loads) may stay in
// flight; everything the next K-tile reads is retired. Staging is
// wave-symmetric so per-wave vmcnt + barrier covers all writers.
// LDS layout (pair-interleaved, 2-way=free on every 16-lane frag phase):
//   element (row,k): p=row>>1, pos=((row&1)*4 + ((k_local)>>3)) ^ (p&7),
//   byte = slot*65536 + (B?32768:0) + ks*16384 + p*128 + pos*16 + (k&7)*2.
// EPI: cols<1024 -> K2[bh][d>>3][m][d&7]; cols>=1024 -> V2[bh][m>>3][d][m&7]
__global__ __launch_bounds__(512, 2) void gemm256_kv8_kernel(
    const unsigned short* __restrict__ A, const unsigned short* __restrict__ Bt,
    unsigned short* __restrict__ K2out, unsigned short* __restrict__ V2out) {
  __shared__ unsigned short lds[65536];  // 128 KB
  const int tid = threadIdx.x;
  const int l = tid & 63;
  const int lq = l & 15, g = l >> 4;
  const int w = tid >> 6;            // 0..7
  const int wm = w >> 2, wn = w & 3;
  // XCD-chunked swizzle (nwg = 512)
  const int nwg = gridDim.x * gridDim.y;
  const int idl = blockIdx.y * gridDim.x + blockIdx.x;
  const int lin = (idl & 7) * (nwg >> 3) + (idl >> 3);
  const int m0 = (lin / gridDim.x) * 256;
  const int n0 = (lin % gridDim.x) * 256;

  // staging source decode (inverse of LDS layout), per thread, j=0/1
  int row0, gg0, row1, gg1;
  { int u = tid;       int p = u >> 3; int t = (u & 7) ^ (p & 7); row0 = 2 * p + (t >> 2); gg0 = t & 3; }
  { int u = 512 + tid; int p = u >> 3; int t = (u & 7) ^ (p & 7); row1 = 2 * p + (t >> 2); gg1 = t & 3; }
  const unsigned short* sA0 = A  + (size_t)(m0 + row0) * 1024 + gg0 * 8;
  const unsigned short* sA1 = A  + (size_t)(m0 + row1) * 1024 + gg1 * 8;
  const unsigned short* sB0 = Bt + (size_t)(n0 + row0) * 1024 + gg0 * 8;
  const unsigned short* sB1 = Bt + (size_t)(n0 + row1) * 1024 + gg1 * 8;
  const int wub = (tid & 448) * 16;  // wave-uniform LDS dest base (lane x16 added by HW)

  // loop-invariant frag byte offsets
  int aoffb[8], boffb[4];
#pragma unroll
  for (int mf = 0; mf < 8; ++mf) {
    int row = wm * 128 + mf * 16 + lq;
    int p = row >> 1;
    int pos = (((row & 1) << 2) + g) ^ (p & 7);
    aoffb[mf] = p * 128 + pos * 16;
  }
#pragma unroll
  for (int nf = 0; nf < 4; ++nf) {
    int row = wn * 64 + nf * 16 + lq;
    int p = row >> 1;
    int pos = (((row & 1) << 2) + g) ^ (p & 7);
    boffb[nf] = 32768 + p * 128 + pos * 16;
  }

  f32x4 acc[8][4] = {};
  short8 af[8];

#define STGA(kt_, ks_, slot_)                                                      \
  do {                                                                             \
    gload_lds16(sA0 + (kt_) * 64 + (ks_) * 32,                                     \
                (char*)lds + (slot_) * 65536 + (ks_) * 16384 + wub);               \
    gload_lds16(sA1 + (kt_) * 64 + (ks_) * 32,                                     \
                (char*)lds + (slot_) * 65536 + (ks_) * 16384 + 8192 + wub);        \
  } while (0)
#define STGB(kt_, ks_, slot_)                                                      \
  do {                                                                             \
    gload_lds16(sB0 + (kt_) * 64 + (ks_) * 32,                                     \
                (char*)lds + (slot_) * 65536 + 32768 + (ks_) * 16384 + wub);       \
    gload_lds16(sB1 + (kt_) * 64 + (ks_) * 32,                                     \
                (char*)lds + (slot_) * 65536 + 32768 + (ks_) * 16384 + 8192 + wub);\
  } while (0)

#define PHASE(slot_, ks_, nfp_, RELA_, STGSTMT, GATESTMT)                          \
  do {                                                                             \
    const char* base_ = (const char*)lds + (slot_) * 65536 + (ks_) * 16384;        \
    if (RELA_) {                                                                   \
      _Pragma("unroll") for (int mf_ = 0; mf_ < 8; ++mf_)                          \
          af[mf_] = *(const short8*)(base_ + aoffb[mf_]);                          \
    }                                                                              \
    short8 bf0_ = *(const short8*)(base_ + boffb[2 * (nfp_) + 0]);                 \
    short8 bf1_ = *(const short8*)(base_ + boffb[2 * (nfp_) + 1]);                 \
    STGSTMT;                                                                       \
    __builtin_amdgcn_s_barrier();                                                  \
    asm volatile("s_waitcnt lgkmcnt(0)" ::: "memory");                             \
    __builtin_amdgcn_sched_barrier(0);                                             \
    __builtin_amdgcn_s_setprio(1);                                                 \
    _Pragma("unroll") for (int mf_ = 0; mf_ < 8; ++mf_) {                          \
      acc[mf_][2 * (nfp_) + 0] = __builtin_amdgcn_mfma_f32_16x16x32_bf16(          \
          af[mf_], bf0_, acc[mf_][2 * (nfp_) + 0], 0, 0, 0);                       \
      acc[mf_][2 * (nfp_) + 1] = __builtin_amdgcn_mfma_f32_16x16x32_bf16(          \
          af[mf_], bf1_, acc[mf_][2 * (nfp_) + 1], 0, 0, 0);                       \
    }                                                                              \
    __builtin_amdgcn_s_setprio(0);                                                 \
    GATESTMT;                                                                      \
    __builtin_amdgcn_s_barrier();                                                  \
  } while (0)

#define GATE4 asm volatile("s_waitcnt vmcnt(4)" ::: "memory")
#define GATE0 asm volatile("s_waitcnt vmcnt(0)" ::: "memory")
#define NOSTMT do {} while (0)

  // prologue: kt0 fully + kt1's k0 halves; gate so kt0 is resident
  STGA(0, 0, 0); STGA(0, 1, 0); STGB(0, 0, 0); STGB(0, 1, 0);
  STGA(1, 0, 1); STGB(1, 0, 1);
  GATE4;
  __builtin_amdgcn_s_barrier();

  // steady iterations: kt = 2it (slot0), 2it+1 (slot1), it = 0..6 (kt 0..13)
  for (int it = 0; it < 7; ++it) {
    const int kt = 2 * it;
    // kt (slot 0)
    PHASE(0, 0, 0, 1, STGA(kt + 1, 1, 1), NOSTMT);
    PHASE(0, 0, 1, 0, STGB(kt + 1, 1, 1), NOSTMT);
    PHASE(0, 1, 0, 1, STGA(kt + 2, 0, 0), NOSTMT);
    PHASE(0, 1, 1, 0, STGB(kt + 2, 0, 0), GATE4);
    // kt+1 (slot 1)
    PHASE(1, 0, 0, 1, STGA(kt + 2, 1, 0), NOSTMT);
    PHASE(1, 0, 1, 0, STGB(kt + 2, 1, 0), NOSTMT);
    PHASE(1, 1, 0, 1, STGA(kt + 3, 0, 1), NOSTMT);
    PHASE(1, 1, 1, 0, STGB(kt + 3, 0, 1), GATE4);
  }
  // tail: kt = 14 (slot 0) stages only kt15's k1; drain at its end
  PHASE(0, 0, 0, 1, STGA(15, 1, 1), NOSTMT);
  PHASE(0, 0, 1, 0, STGB(15, 1, 1), NOSTMT);
  PHASE(0, 1, 0, 1, NOSTMT, NOSTMT);
  PHASE(0, 1, 1, 0, NOSTMT, GATE0);
  // kt = 15 (slot 1): no staging, no gates
  PHASE(1, 0, 0, 1, NOSTMT, NOSTMT);
  PHASE(1, 0, 1, 0, NOSTMT, NOSTMT);
  PHASE(1, 1, 0, 1, NOSTMT, NOSTMT);
  PHASE(1, 1, 1, 0, NOSTMT, NOSTMT);

#undef PHASE
#undef STGA
#undef STGB
#undef GATE4
#undef GATE0
#undef NOSTMT

  // epilogue (round-12 verified): K2/V2 scatter
#pragma unroll
  for (int mt = 0; mt < 8; ++mt) {
#pragma unroll
    for (int nt = 0; nt < 4; ++nt) {
      int col = n0 + wn * 64 + nt * 16 + lq;
      int rowb = m0 + wm * 128 + mt * 16 + g * 4;
      int b = rowb >> 12, mm = rowb & 4095;
      if (col < 1024) {
        int h = col >> 6, d = col & 63;
#pragma unroll
        for (int r = 0; r < 4; ++r) {
          size_t off =
              (((size_t)(b * 16 + h) * 8 + (d >> 3)) * 4096 + (mm + r)) * 8 + (d & 7);
          K2out[off] = f2bf(acc[mt][nt][r]);
        }
      } else {
        int hv = col - 1024;
        int h = hv >> 6, d = hv & 63;
        ushort4 pk;
        pk.x = f2bf(acc[mt][nt][0]);
        pk.y = f2bf(acc[mt][nt][1]);
        pk.z = f2bf(acc[mt][nt][2]);
        pk.w = f2bf(acc[mt][nt][3]);
        size_t off = (((size_t)(b * 16 + h) * 512 + (mm >> 3)) * 64 + d) * 8 + (mm & 7);
        *(ushort4*)&V2out[off] = pk;
      }
    }
  }
}

// ---------------- fused attention (two-phase halves, in-register P) ----------------
// Round-13 verified: conflict-free d-block-major LDS, sigma-permuted K,
// in-register P, zero-shuffle PV, mask as MFMA C-seed, Q prescaled, KVBLK=64
// dbuf, two-phase halves, 4-way den chains, truncate pack.
__global__ __launch_bounds__(256, 3) void attn_kernel(
    const unsigned short* __restrict__ K2, const unsigned short* __restrict__ V2,
    const unsigned short* __restrict__ Q, const float* __restrict__ maskb,
    unsigned short* __restrict__ numP, float* __restrict__ denP) {
  __shared__ unsigned short Ks[2][8 * 64 * 8];  // [buf][db][jj (sigma'd)][8 d-elems]
  __shared__ unsigned short Vt[2][8 * 64 * 8];  // [buf][jb][d][8 j-elems]

  const int tid = threadIdx.x;
  const int l = tid & 63, w = tid >> 6;
  const int lq = l & 31;  // q within the wave's 32-row block / row index
  const int hi = l >> 5;  // lane half

  // XCD-affine decode: id&7 = XCD; 8 consecutive same-XCD blocks share (bh,js)
  const int id = blockIdx.x;
  const int xcd = id & 7;
  const int kk = id >> 3;
  const int qi = kk & 7;
  const int pr = xcd * 32 + (kk >> 3);
  const int bh = pr & 63, js = pr >> 6;
  const int b = bh >> 4;
  const int q0 = qi * 128 + w * 32;

  const unsigned short* Qh = Q + (size_t)bh * 1024 * 64;
  const unsigned short* Kh = K2 + (size_t)bh * 8 * 4096 * 8;   // [db][m][8]
  const unsigned short* Vh = V2 + (size_t)bh * 512 * 64 * 8;   // [jb][d][8]
  const float* bb = maskb + b * 4096;

  const float CLIP2 = 7.213475204444817f;  // 5 * log2(e)

  // Q fragments (B-operand): lane holds Q[q0+lq][kc*16 + hi*8 + e], prescaled
  short8 qf[4];
#pragma unroll
  for (int kc = 0; kc < 4; ++kc)
    qf[kc] = *(const short8*)&Qh[(size_t)(q0 + lq) * 64 + kc * 16 + hi * 8];

  f32x16 oacc[2] = {};
  float den4[4] = {};

  const int jbeg = js * 16, jend = jbeg + 16;  // 16 tiles of 64 j

#define STAGE_KV(bi_, j0_)                                                       \
  do {                                                                           \
    _Pragma("unroll") for (int t = 0; t < 2; ++t) {                              \
      int c = t * 256 + tid;                                                     \
      int db = c >> 6, jj = c & 63;                                              \
      int sig = (jj & 0x33) | ((jj & 4) << 1) | ((jj & 8) >> 1);                 \
      char* lk = (char*)(&Ks[bi_][0]) + t * 4096 + (tid & 192) * 16;             \
      gload_lds16((const char*)(Kh + ((size_t)db * 4096 + (j0_) + sig) * 8), lk);\
      char* lv = (char*)(&Vt[bi_][0]) + t * 4096 + (tid & 192) * 16;             \
      gload_lds16((const char*)(Vh + ((size_t)(((j0_) >> 3) + db) * 64 + jj) * 8), lv); \
    }                                                                            \
  } while (0)

  // prologue: stage first tile into buf 0
  STAGE_KV(0, jbeg * 64);
  __syncthreads();

  for (int jt = jbeg; jt < jend; ++jt) {
    const int j0 = jt * 64;
    const int cur = jt & 1;  // jbeg is even (js*16)
    if (jt + 1 < jend) STAGE_KV(cur ^ 1, j0 + 64);

    const unsigned short* Kc = &Ks[cur][0];
    const unsigned short* Vc = &Vt[cur][0];

    // ---- seeds for BOTH halves (mask bias at sigma-mapped reg position) ----
    f32x16 s0, s1;
#pragma unroll
    for (int bq = 0; bq < 4; ++bq) {
      int boffm = j0 + ((bq & 1) << 2) + (hi << 3) + ((bq >> 1) << 4);
      f32x4 m4a = *(const f32x4*)&bb[boffm];
      f32x4 m4b = *(const f32x4*)&bb[boffm + 32];
#pragma unroll
      for (int e = 0; e < 4; ++e) {
        s0[bq * 4 + e] = m4a[e];
        s1[bq * 4 + e] = m4b[e];
      }
    }
    // ---- QK^T both halves (conflict-free A-frag reads) ----
    __builtin_amdgcn_s_setprio(1);
#pragma unroll
    for (int kc = 0; kc < 4; ++kc) {
      short8 kf0 = *(const short8*)((const char*)Kc + (2 * kc + hi) * 1024 + lq * 16);
      s0 = __builtin_amdgcn_mfma_f32_32x32x16_bf16(kf0, qf[kc], s0, 0, 0, 0);
    }
#pragma unroll
    for (int kc = 0; kc < 4; ++kc) {
      short8 kf1 = *(const short8*)((const char*)Kc + (2 * kc + hi) * 1024 + (32 + lq) * 16);
      s1 = __builtin_amdgcn_mfma_f32_32x32x16_bf16(kf1, qf[kc], s1, 0, 0, 0);
    }
    __builtin_amdgcn_s_setprio(0);
    // ---- softmax both halves (clamp via med3, exp2, 4-way den chains) ----
#pragma unroll
    for (int r = 0; r < 16; ++r) {
      float p = __builtin_amdgcn_exp2f(__builtin_amdgcn_fmed3f(s0[r], -CLIP2, CLIP2));
      den4[r & 3] += p;
      s0[r] = p;
    }
#pragma unroll
    for (int r = 0; r < 16; ++r) {
      float p = __builtin_amdgcn_exp2f(__builtin_amdgcn_fmed3f(s1[r], -CLIP2, CLIP2));
      den4[r & 3] += p;
      s1[r] = p;
    }
    // ---- pack both halves (truncate, 1 op/pair) ----
    unsigned int w0[8], w1[8];
#pragma unroll
    for (int i = 0; i < 8; ++i) w0[i] = pack_trunc(s0[i * 2], s0[i * 2 + 1]);
#pragma unroll
    for (int i = 0; i < 8; ++i) w1[i] = pack_trunc(s1[i * 2], s1[i * 2 + 1]);
    // ---- PV both halves ----
    __builtin_amdgcn_s_setprio(1);
#pragma unroll
    for (int kt = 0; kt < 2; ++kt) {
      union { unsigned int u[4]; short8 s; } pa;
      pa.u[0] = w0[kt * 4 + 0];
      pa.u[1] = w0[kt * 4 + 1];
      pa.u[2] = w0[kt * 4 + 2];
      pa.u[3] = w0[kt * 4 + 3];
#pragma unroll
      for (int dt = 0; dt < 2; ++dt) {
        short8 vf = *(const short8*)((const char*)Vc +
            (2 * kt + hi) * 1024 + (dt * 32 + lq) * 16);
        oacc[dt] = __builtin_amdgcn_mfma_f32_32x32x16_bf16(pa.s, vf, oacc[dt], 0, 0, 0);
      }
    }
#pragma unroll
    for (int kt = 0; kt < 2; ++kt) {
      union { unsigned int u[4]; short8 s; } pa;
      pa.u[0] = w1[kt * 4 + 0];
      pa.u[1] = w1[kt * 4 + 1];
      pa.u[2] = w1[kt * 4 + 2];
      pa.u[3] = w1[kt * 4 + 3];
#pragma unroll
      for (int dt = 0; dt < 2; ++dt) {
        short8 vf = *(const short8*)((const char*)Vc +
            (4 + 2 * kt + hi) * 1024 + (dt * 32 + lq) * 16);
        oacc[dt] = __builtin_amdgcn_mfma_f32_32x32x16_bf16(pa.s, vf, oacc[dt], 0, 0, 0);
      }
    }
    __builtin_amdgcn_s_setprio(0);
    // barrier: drains (already-landed) next-tile staging; protects buf reuse
    __syncthreads();
  }
#undef STAGE_KV

  // denominator: lanes l and l^32 hold disjoint j-sums for the same q
  float den = (den4[0] + den4[1]) + (den4[2] + den4[3]);
  den += __shfl_xor(den, 32);
  if (l < 32) denP[(((size_t)js * 64 + bh) * 1024) + q0 + l] = den;

  // numerator partials: q from reg index (PV C-layout), d from lane
#pragma unroll
  for (int dt = 0; dt < 2; ++dt)
#pragma unroll
    for (int r = 0; r < 16; ++r) {
      int q = q0 + (r & 3) + 8 * (r >> 2) + 4 * hi;
      int d = dt * 32 + lq;
      numP[((((size_t)js * 64 + bh) * 1024 + q) * 64) + d] = f2bf(oacc[dt][r]);
    }
}

// ---------------- combine j-split partials, divide, write Ob ----------------
__global__ __launch_bounds__(256) void attn_reduce_kernel(
    const unsigned short* __restrict__ numP, const float* __restrict__ denP,
    unsigned short* __restrict__ Ob) {
  int id = blockIdx.x * 256 + threadIdx.x;  // 0 .. 524287
  int d8 = id & 7;
  int q = (id >> 3) & 1023;
  int bh = id >> 13;
  int b = bh >> 4, h = bh & 15;
  float den = 0.f;
  float o[8] = {0.f, 0.f, 0.f, 0.f, 0.f, 0.f, 0.f, 0.f};
#pragma unroll
  for (int s = 0; s < 4; ++s) {
    const unsigned short* np =
        numP + ((((size_t)s * 64 + bh) * 1024 + q) * 64 + d8 * 8);
    u16x8 v = *(const u16x8*)np;
    den += denP[((size_t)s * 64 + bh) * 1024 + q];
#pragma unroll
    for (int e = 0; e < 8; ++e) o[e] += bf2f(v[e]);
  }
  float r = 1.0f / den;
  u16x8 outv;
#pragma unroll
  for (int e = 0; e < 8; ++e) outv[e] = f2bf(o[e] * r);
  *(u16x8*)&Ob[(((size_t)b * 1024 + q) * 1024) + h * 64 + d8 * 8] = outv;
}

// ---------------- launcher ----------------
extern "C" void kernel_launch(void* const* d_in, const int* in_sizes, int n_in,
                              void* d_out, int out_size, void* d_ws, size_t ws_size,
                              hipStream_t stream) {
  (void)in_sizes; (void)n_in; (void)out_size; (void)ws_size;
  const float* x    = (const float*)d_in[0];
  const float* ctx  = (const float*)d_in[1];
  const int*   mask = (const int*)d_in[2];
  const float* Wq   = (const float*)d_in[3];
  const float* Wkv  = (const float*)d_in[4];
  const float* Wo   = (const float*)d_in[5];
  const float* bo   = (const float*)d_in[6];
  float* out = (float*)d_out;

  char* ws = (char*)d_ws;
  const size_t MB = 1 << 20;
  // 0..40 MiB region is time-shared: {xb, cb} before attention; {numP, denP,
  // maskbias} after cb is consumed by the KV-GEMM (stream-ordered).
  unsigned short* numP = (unsigned short*)(ws + 0);        // 32 MiB : [4][64][1024][64] bf16
  float*          denP = (float*)(ws + 32 * MB);           // 1 MiB  : [4][64][1024] fp32
  float*          mbias= (float*)(ws + 33 * MB);           // 64 KiB : [4][4096] fp32
  unsigned short* xb   = (unsigned short*)(ws + 0);        // 8 MiB  : x bf16 [4096][1024]
  unsigned short* cb   = (unsigned short*)(ws + 8 * MB);   // 32 MiB : ctx bf16 [16384][1024]
  unsigned short* WqT  = (unsigned short*)(ws + 40 * MB);  // 2 MiB
  unsigned short* WkvT = (unsigned short*)(ws + 42 * MB);  // 4 MiB
  unsigned short* WoT  = (unsigned short*)(ws + 46 * MB);  // 2 MiB
  unsigned short* Qb   = (unsigned short*)(ws + 48 * MB);  // 8 MiB  : [bh][1024][64] (prescaled)
  unsigned short* K2   = (unsigned short*)(ws + 56 * MB);  // 32 MiB : [bh][d/8][4096][8]
  unsigned short* V2   = (unsigned short*)(ws + 88 * MB);  // 32 MiB : [bh][m/8][64][8]
  unsigned short* Ob   = (unsigned short*)(ws + 120 * MB); // 8 MiB  : [b][n][1024]

  cast_bf16_kernel<<<2048, 256, 0, stream>>>(x, xb, (4 * 1024 * 1024) / 8);
  cast_bf16_kernel<<<2048, 256, 0, stream>>>(ctx, cb, (16 * 1024 * 1024) / 8);
  transpose_cast_kernel<<<dim3(32, 32), 256, 0, stream>>>(Wq, WqT, 1024, 1024);
  transpose_cast_kernel<<<dim3(64, 32), 256, 0, stream>>>(Wkv, WkvT, 1024, 2048);
  transpose_cast_kernel<<<dim3(32, 32), 256, 0, stream>>>(Wo, WoT, 1024, 1024);

  gemm_bt_kernel<0><<<dim3(8, 32), 256, 0, stream>>>(xb, WqT, 4096, 1024, 1024,
                                                     Qb, (float*)nullptr,
                                                     (const float*)nullptr);
  gemm256_kv8_kernel<<<dim3(8, 64), 512, 0, stream>>>(cb, WkvT, K2, V2);
  // mbias overlaps the (now-dead) cb region; launched after the KV-GEMM reads cb
  mask_bias_kernel<<<64, 256, 0, stream>>>(mask, mbias, 4 * 4096);
  attn_kernel<<<2048, 256, 0, stream>>>(K2, V2, Qb, mbias, numP, denP);
  attn_reduce_kernel<<<2048, 256, 0, stream>>>(numP, denP, Ob);
  gemm_bt_kernel<2><<<dim3(8, 32), 256, 0, stream>>>(Ob, WoT, 4096, 1024, 1024,
                                                     (unsigned short*)nullptr,
                                                     out, bo);
}